// Round 5
// baseline (1293.525 us; speedup 1.0000x reference)
//
#include <hip/hip_runtime.h>
#include <cstdint>
#include <cstddef>

#define B_   16
#define N_   2048
#define D_   128
#define F_   1024
#define H1_  512
#define OUT_ 50

static constexpr float BN_EPS = 1e-5f;

typedef __attribute__((ext_vector_type(8))) short short8;
typedef __attribute__((ext_vector_type(4))) float f32x4;

__device__ inline unsigned short f2bf(float f) {
  union { float f; unsigned u; } v; v.f = f;
  unsigned r = v.u + 0x7fff + ((v.u >> 16) & 1);
  return (unsigned short)(r >> 16);
}

// async global->LDS, 16B per lane; LDS dest = wave-uniform base + lane*16
__device__ inline void dma16(const unsigned short* g, unsigned short* l) {
  __builtin_amdgcn_global_load_lds(
      (const __attribute__((address_space(1))) unsigned int*)g,
      (__attribute__((address_space(3))) unsigned int*)l, 16, 0, 0);
}

// ---------------------------------------------------------------------------
__global__ void cast2d_k(const float* __restrict__ src, unsigned short* __restrict__ dst,
                         int R, int C, int ldSrc) {
  long i = (long)blockIdx.x * 256 + threadIdx.x;
  if (i >= (long)R * C) return;
  int r = (int)(i / C), c = (int)(i % C);
  dst[i] = f2bf(src[(long)r * ldSrc + c]);
}

// ---------------------------------------------------------------------------
// conv1 (3->128) + bn + relu -> bf16 token-major. grid (N, g), block 128
// ---------------------------------------------------------------------------
__global__ void conv1_k(const float* __restrict__ x, const float* __restrict__ w1,
                        const float* __restrict__ g, const float* __restrict__ bb,
                        const float* __restrict__ m, const float* __restrict__ v,
                        unsigned short* __restrict__ h0b) {
  int o = threadIdx.x, n = blockIdx.x, b = blockIdx.y;
  const float* xb = x + (long)b * 3 * N_;
  float val = w1[o * 3 + 0] * xb[n] + w1[o * 3 + 1] * xb[N_ + n] + w1[o * 3 + 2] * xb[2 * N_ + n];
  float sc = g[o] * rsqrtf(v[o] + BN_EPS);
  val = val * sc + (bb[o] - m[o] * sc);
  h0b[((long)b * N_ + n) * D_ + o] = f2bf(fmaxf(val, 0.f));
}

// ---------------------------------------------------------------------------
// bf16 MFMA GEMM. out[n][o] = epi( sum_k A[n][k]*W[o][k] )
// A bf16 token-major (ldA), W bf16 [O][K] (ldW). DMA staging, XOR swizzle.
// Tile 128x128, BK=64, block 256 (2x2 waves).
// flags: 1 outF token fp32 | 2 outF channel fp32 | 4 outH token bf16 |
//        16 add res (fp32 token) after act | 32 pool partials | 64 kv-split
// Token-bf16 outputs go through an LDS repack -> 16B vector stores.
// ---------------------------------------------------------------------------
__global__ __launch_bounds__(256)
void gemm_bf(const unsigned short* __restrict__ Wb, int ldW,
             const unsigned short* __restrict__ A, long sA, int ldA,
             const float* __restrict__ bias, const float* __restrict__ bias2,
             const float* __restrict__ perBO, int ldPBO,
             const float* __restrict__ bng, const float* __restrict__ bnb,
             const float* __restrict__ bnm, const float* __restrict__ bnv,
             const float* __restrict__ res, long sRes, int ldRes,
             float* __restrict__ outF, long sOutF, int ldOutF,
             unsigned short* __restrict__ outH, long sOutH, int ldOutH,
             unsigned short* __restrict__ outH2, long sOutH2, int ldOutH2,
             float* __restrict__ pmax, float* __restrict__ psum,
             int K, int O, int act, int flags) {
  __shared__ unsigned short lAB[16384];       // lA = [0..8191], lB = [8192..]
  __shared__ float lpm[4][64], lps[4][64];
  unsigned short* lA = lAB;
  unsigned short* lB = lAB + 8192;
  unsigned short* lS = lAB;                   // repack tile, stride 132 (8448 shorts)
  int tid = threadIdx.x;
  int n0 = blockIdx.x * 128, o0 = blockIdx.y * 128, b = blockIdx.z;
  int wave = tid >> 6, lane = tid & 63;
  int wr = wave >> 1, wc = wave & 1;
  int quad = lane >> 4, l15 = lane & 15;
  int rowL = lane >> 3;
  int kseg = (lane & 7) ^ rowL;
  const unsigned short* Ab = A + (long)b * sA + (long)n0 * ldA;
  const unsigned short* Wp = Wb + (long)o0 * ldW;

  f32x4 acc[4][4];
  #pragma unroll
  for (int i = 0; i < 4; ++i)
    #pragma unroll
    for (int j = 0; j < 4; ++j) acc[i][j] = (f32x4){0.f, 0.f, 0.f, 0.f};

  for (int kc = 0; kc < K; kc += 64) {
    #pragma unroll
    for (int t = 0; t < 4; ++t) {
      int chunk = t * 4 + wave;
      int row = chunk * 8 + rowL;
      dma16(Ab + (long)row * ldA + kc + kseg * 8, &lA[chunk * 512]);
      dma16(Wp + (long)row * ldW + kc + kseg * 8, &lB[chunk * 512]);
    }
    __syncthreads();
    #pragma unroll
    for (int kk = 0; kk < 2; ++kk) {
      short8 af[4], bf[4];
      #pragma unroll
      for (int mt = 0; mt < 4; ++mt) {
        int r = wr * 64 + mt * 16 + l15;
        af[mt] = *(const short8*)&lA[r * 64 + (((kk * 4 + quad) ^ (l15 & 7)) * 8)];
      }
      #pragma unroll
      for (int ot = 0; ot < 4; ++ot) {
        int r = wc * 64 + ot * 16 + l15;
        bf[ot] = *(const short8*)&lB[r * 64 + (((kk * 4 + quad) ^ (l15 & 7)) * 8)];
      }
      #pragma unroll
      for (int mt = 0; mt < 4; ++mt)
        #pragma unroll
        for (int ot = 0; ot < 4; ++ot)
          acc[mt][ot] = __builtin_amdgcn_mfma_f32_16x16x32_bf16(af[mt], bf[ot], acc[mt][ot], 0, 0, 0);
    }
    __syncthreads();
  }

  bool isV = (flags & 64) && (o0 >= 128);
  bool tokenH = ((flags & 4) != 0) || ((flags & 64) && !isV);

  if (!tokenH) {
    // channel-major paths: ws2 fp32 (flags&2) or xvb bf16 (isV)
    #pragma unroll
    for (int ot = 0; ot < 4; ++ot) {
      int o = o0 + wc * 64 + ot * 16 + l15;
      if (o >= O) continue;
      float bi = 0.f, sc = 1.f, sh = 0.f;
      if (flags & 64) { bi = bias2[o - 128]; }
      else if (bias) bi = bias[o];
      if (perBO) bi += perBO[(long)b * ldPBO + o];
      if (bng) { sc = bng[o] * rsqrtf(bnv[o] + BN_EPS); sh = bnb[o] - bnm[o] * sc; }
      #pragma unroll
      for (int mt = 0; mt < 4; ++mt) {
        int nb = n0 + wr * 64 + mt * 16 + quad * 4;
        float vals[4];
        #pragma unroll
        for (int r = 0; r < 4; ++r) {
          float val = acc[mt][ot][r] + bi;
          val = val * sc + sh;
          if (act == 1)      val = fmaxf(val, 0.f);
          else if (act == 2) val = (val >= 0.f) ? val : 0.2f * val;
          vals[r] = val;
        }
        if (isV) {
          unsigned short t[4];
          #pragma unroll
          for (int r = 0; r < 4; ++r) t[r] = f2bf(vals[r]);
          *(uint2*)&outH2[(long)b * sOutH2 + (long)(o - 128) * ldOutH2 + nb] = *(uint2*)&t[0];
        } else {
          *(float4*)&outF[(long)b * sOutF + (long)o * ldOutF + nb] = *(float4*)vals;
        }
      }
    }
    return;
  }

  float colMax[4], colSum[4];
  #pragma unroll
  for (int ot = 0; ot < 4; ++ot) { colMax[ot] = -1e30f; colSum[ot] = 0.f; }

  for (int h = 0; h < 2; ++h) {
    __syncthreads();
    if (wr == h) {
      #pragma unroll
      for (int ot = 0; ot < 4; ++ot) {
        int o = o0 + wc * 64 + ot * 16 + l15;
        float bi = 0.f, sc = 1.f, sh = 0.f;
        bool valid = (o < O);
        if (valid) {
          if (!(flags & 64) && bias) bi = bias[o];
          if (perBO) bi += perBO[(long)b * ldPBO + o];
          if (bng) { sc = bng[o] * rsqrtf(bnv[o] + BN_EPS); sh = bnb[o] - bnm[o] * sc; }
        }
        #pragma unroll
        for (int mt = 0; mt < 4; ++mt) {
          int nb = n0 + wr * 64 + mt * 16 + quad * 4;
          #pragma unroll
          for (int r = 0; r < 4; ++r) {
            float val = acc[mt][ot][r] + bi;
            val = val * sc + sh;
            if (act == 1)      val = fmaxf(val, 0.f);
            else if (act == 2) val = (val >= 0.f) ? val : 0.2f * val;
            if (flags & 16) val += res[(long)b * sRes + (long)(nb + r) * ldRes + o];
            if ((flags & 1) && valid)
              outF[(long)b * sOutF + (long)(nb + r) * ldOutF + o] = val;
            if (flags & 32) { colMax[ot] = fmaxf(colMax[ot], val); colSum[ot] += val; }
            lS[(mt * 16 + quad * 4 + r) * 132 + wc * 64 + ot * 16 + l15] = f2bf(val);
          }
        }
      }
    }
    __syncthreads();
    {
      int r = tid >> 2, c0 = (tid & 3) * 32;
      long gbase = (long)b * sOutH + (long)(n0 + h * 64 + r) * ldOutH + o0;
      #pragma unroll
      for (int s = 0; s < 4; ++s) {
        short8 vv = *(const short8*)&lS[r * 132 + c0 + s * 8];
        *(short8*)&outH[gbase + c0 + s * 8] = vv;
      }
    }
  }

  if (flags & 32) {
    #pragma unroll
    for (int ot = 0; ot < 4; ++ot) {
      float m = colMax[ot], s = colSum[ot];
      m = fmaxf(m, __shfl_xor(m, 16)); s += __shfl_xor(s, 16);
      m = fmaxf(m, __shfl_xor(m, 32)); s += __shfl_xor(s, 32);
      if (quad == 0) { lpm[wave][ot * 16 + l15] = m; lps[wave][ot * 16 + l15] = s; }
    }
    __syncthreads();
    if (tid < 128) {
      int wcx = tid >> 6, ol = tid & 63;
      float m = fmaxf(lpm[wcx][ol], lpm[wcx + 2][ol]);
      float s = lps[wcx][ol] + lps[wcx + 2][ol];
      int o = o0 + wcx * 64 + ol;
      pmax[((long)b * 16 + blockIdx.x) * 1024 + o] = m;
      psum[((long)b * 16 + blockIdx.x) * 1024 + o] = s;
    }
  }
}

// ---------------------------------------------------------------------------
// Gram row-stats -> lw[n] = mx[n] + log(rs[n]).  E = xk xk^T, K=128.
// xk bf16 token [2048][128]; DMA-staged swizzled LDS. grid (32, g), block 256.
// ---------------------------------------------------------------------------
__global__ __launch_bounds__(256)
void gram_lw(const unsigned short* __restrict__ xk, long sXk,
             float* __restrict__ lw) {
  __shared__ unsigned short lK[64 * 128];   // 16KB, 16-seg swizzle
  int tid = threadIdx.x, wave = tid >> 6, lane = tid & 63;
  int quad = lane >> 4, l15 = lane & 15;
  int rowL4 = lane >> 4, s16 = lane & 15;
  int n0 = blockIdx.x * 64, b = blockIdx.y;
  const unsigned short* Kp = xk + (long)b * sXk;
  short8 afr[4];
  {
    const unsigned short* arow = Kp + (long)(n0 + wave * 16 + l15) * 128;
    #pragma unroll
    for (int kf = 0; kf < 4; ++kf) afr[kf] = *(const short8*)(arow + kf * 32 + quad * 8);
  }
  float runm[4], runs[4];
  #pragma unroll
  for (int r = 0; r < 4; ++r) { runm[r] = -1e30f; runs[r] = 0.f; }

  for (int m0 = 0; m0 < 2048; m0 += 64) {
    __syncthreads();
    #pragma unroll
    for (int t = 0; t < 4; ++t) {
      int c = t * 4 + wave;
      int row = c * 4 + rowL4;
      int gseg = (s16 & 8) | ((s16 ^ (row & 7)) & 7);
      dma16(Kp + (long)(m0 + row) * 128 + gseg * 8, &lK[c * 512]);
    }
    __syncthreads();
    #pragma unroll
    for (int mf = 0; mf < 4; ++mf) {
      f32x4 s = (f32x4){0.f, 0.f, 0.f, 0.f};
      #pragma unroll
      for (int kf = 0; kf < 4; ++kf) {
        int r = mf * 16 + l15, q = kf * 4 + quad;
        int sp = (q & 8) | ((q ^ (r & 7)) & 7);
        short8 bfr = *(const short8*)&lK[r * 128 + sp * 8];
        s = __builtin_amdgcn_mfma_f32_16x16x32_bf16(afr[kf], bfr, s, 0, 0, 0);
      }
      #pragma unroll
      for (int r = 0; r < 4; ++r) {
        float e = s[r];
        float mn = fmaxf(runm[r], e);
        runs[r] = runs[r] * __expf(runm[r] - mn) + __expf(e - mn);
        runm[r] = mn;
      }
    }
  }
  #pragma unroll
  for (int r = 0; r < 4; ++r) {
    float m = runm[r], s = runs[r];
    #pragma unroll
    for (int off = 1; off < 16; off <<= 1) {
      float mo = __shfl_xor(m, off), so = __shfl_xor(s, off);
      float mn = fmaxf(m, mo);
      s = s * __expf(m - mn) + so * __expf(mo - mn);
      m = mn;
    }
    if (l15 == 0) {
      int n = n0 + wave * 16 + quad * 4 + r;
      lw[(long)b * 2048 + n] = m + __logf(s);
    }
  }
}

// ---------------------------------------------------------------------------
// Fused PV: p[m][n] = exp(E[m][n] - lw[n]);  cs[m] = sum_n p;
// xrb[m][d] = bf16( li[m][d] - (sum_n p[m][n]*xv[d][n]) / (1e-9+cs[m]) )
// grid (32, g), block 256.
// ---------------------------------------------------------------------------
__global__ __launch_bounds__(256)
void pv_k(const unsigned short* __restrict__ xk, long sXk,
          const unsigned short* __restrict__ xv, long sXv,
          const float* __restrict__ lw,
          const float* __restrict__ li, long sLi, int ldLi,
          unsigned short* __restrict__ xrb, long sXr) {
  __shared__ unsigned short lK[64 * 128];   // 16KB, 16-seg swizzle
  __shared__ unsigned short lV[128 * 64];   // 16KB, 8-seg swizzle
  __shared__ unsigned short lP[4][16 * 72];
  __shared__ float lwt[64];
  int tid = threadIdx.x, wave = tid >> 6, lane = tid & 63;
  int quad = lane >> 4, l15 = lane & 15;
  int rowL4 = lane >> 4, s16 = lane & 15;
  int rowL8 = lane >> 3, s8 = lane & 7;
  int m0 = blockIdx.x * 64, b = blockIdx.y;
  const unsigned short* Kp = xk + (long)b * sXk;
  const unsigned short* Vp = xv + (long)b * sXv;
  short8 akr[4];
  {
    const unsigned short* arow = Kp + (long)(m0 + wave * 16 + l15) * 128;
    #pragma unroll
    for (int kf = 0; kf < 4; ++kf) akr[kf] = *(const short8*)(arow + kf * 32 + quad * 8);
  }
  f32x4 acc[8];
  #pragma unroll
  for (int dt = 0; dt < 8; ++dt) acc[dt] = (f32x4){0.f, 0.f, 0.f, 0.f};
  float runc[4] = {0.f, 0.f, 0.f, 0.f};

  for (int n0c = 0; n0c < 2048; n0c += 64) {
    __syncthreads();
    #pragma unroll
    for (int t = 0; t < 4; ++t) {
      int cK = t * 4 + wave;
      int rowK = cK * 4 + rowL4;
      int gsegK = (s16 & 8) | ((s16 ^ (rowK & 7)) & 7);
      dma16(Kp + (long)(n0c + rowK) * 128 + gsegK * 8, &lK[cK * 512]);
      int cV = t * 4 + wave;
      int rowV = cV * 8 + rowL8;
      int gsegV = s8 ^ (rowV & 7);
      dma16(Vp + (long)rowV * 2048 + n0c + gsegV * 8, &lV[cV * 512]);
    }
    if (tid < 64) lwt[tid] = lw[(long)b * 2048 + n0c + tid];
    __syncthreads();
    #pragma unroll
    for (int nf = 0; nf < 4; ++nf) {
      f32x4 s = (f32x4){0.f, 0.f, 0.f, 0.f};
      #pragma unroll
      for (int kf = 0; kf < 4; ++kf) {
        int r = nf * 16 + l15, q = kf * 4 + quad;
        int sp = (q & 8) | ((q ^ (r & 7)) & 7);
        short8 bfr = *(const short8*)&lK[r * 128 + sp * 8];
        s = __builtin_amdgcn_mfma_f32_16x16x32_bf16(akr[kf], bfr, s, 0, 0, 0);
      }
      float lwc = lwt[nf * 16 + l15];
      #pragma unroll
      for (int r = 0; r < 4; ++r) {
        float p = __expf(s[r] - lwc);
        runc[r] += p;
        lP[wave][(quad * 4 + r) * 72 + nf * 16 + l15] = f2bf(p);
      }
    }
    __syncthreads();
    #pragma unroll
    for (int kc = 0; kc < 2; ++kc) {
      short8 pa = *(const short8*)&lP[wave][l15 * 72 + kc * 32 + quad * 8];
      #pragma unroll
      for (int dt = 0; dt < 8; ++dt) {
        int r = dt * 16 + l15, q = kc * 4 + quad;
        int sp = q ^ (r & 7);
        short8 vb = *(const short8*)&lV[r * 64 + sp * 8];
        acc[dt] = __builtin_amdgcn_mfma_f32_16x16x32_bf16(pa, vb, acc[dt], 0, 0, 0);
      }
    }
  }
  float inv[4];
  #pragma unroll
  for (int r = 0; r < 4; ++r) {
    float s = runc[r];
    #pragma unroll
    for (int off = 1; off < 16; off <<= 1) s += __shfl_xor(s, off);
    inv[r] = 1.f / (1e-9f + s);
  }
  #pragma unroll
  for (int dt = 0; dt < 8; ++dt) {
    int d = dt * 16 + l15;
    #pragma unroll
    for (int r = 0; r < 4; ++r) {
      int m = m0 + wave * 16 + quad * 4 + r;
      float lv = li[(long)b * sLi + (long)m * ldLi + d];
      xrb[(long)b * sXr + (long)m * 128 + d] = f2bf(lv - acc[dt][r] * inv[r]);
    }
  }
}

// ---------------------------------------------------------------------------
__global__ void poolred_k(const float* __restrict__ pmax, const float* __restrict__ psum,
                          float* __restrict__ xmax, float* __restrict__ xavg) {
  int f = blockIdx.x * 256 + threadIdx.x, b = blockIdx.y;
  float mx = -1e30f, s = 0.f;
  #pragma unroll
  for (int t = 0; t < 16; ++t) {
    mx = fmaxf(mx, pmax[((long)b * 16 + t) * 1024 + f]);
    s += psum[((long)b * 16 + t) * 1024 + f];
  }
  xmax[(long)b * 1024 + f] = mx;
  xavg[(long)b * 1024 + f] = s * (1.f / 2048.f);
}

__global__ __launch_bounds__(256)
void poolterm_k(const float* __restrict__ ws1, const float* __restrict__ xmax,
                const float* __restrict__ xavg, float* __restrict__ pt) {
  int o = blockIdx.x, b = blockIdx.y, tid = threadIdx.x;
  const float* w = ws1 + (long)o * 3072;
  float s = 0.f;
  #pragma unroll
  for (int it = 0; it < 4; ++it) {
    int c = tid + it * 256;
    s += w[1024 + c] * xmax[(long)b * 1024 + c] + w[2048 + c] * xavg[(long)b * 1024 + c];
  }
  #pragma unroll
  for (int off = 32; off; off >>= 1) s += __shfl_xor(s, off);
  __shared__ float rsm[4];
  if ((tid & 63) == 0) rsm[tid >> 6] = s;
  __syncthreads();
  if (tid == 0) pt[(long)b * H1_ + o] = rsm[0] + rsm[1] + rsm[2] + rsm[3];
}

// ---------------------------------------------------------------------------
extern "C" void kernel_launch(void* const* d_in, const int* in_sizes, int n_in,
                              void* d_out, int out_size, void* d_ws, size_t ws_size,
                              hipStream_t stream) {
  const float* x      = (const float*)d_in[0];
  const float* w1     = (const float*)d_in[1];
  const float* w2     = (const float*)d_in[2];
  const float* bn1_g  = (const float*)d_in[3];
  const float* bn1_b  = (const float*)d_in[4];
  const float* bn1_m  = (const float*)d_in[5];
  const float* bn1_v  = (const float*)d_in[6];
  const float* bn2_g  = (const float*)d_in[7];
  const float* bn2_b  = (const float*)d_in[8];
  const float* bn2_m  = (const float*)d_in[9];
  const float* bn2_v  = (const float*)d_in[10];
  const float* sa_wqk = (const float*)d_in[11];
  const float* sa_wv  = (const float*)d_in[12];
  const float* sa_bv  = (const float*)d_in[13];
  const float* sa_wt  = (const float*)d_in[14];
  const float* sa_bt  = (const float*)d_in[15];
  const float* sa_g   = (const float*)d_in[16];
  const float* sa_b   = (const float*)d_in[17];
  const float* sa_m   = (const float*)d_in[18];
  const float* sa_v   = (const float*)d_in[19];
  const float* wf     = (const float*)d_in[20];
  const float* bnf_g  = (const float*)d_in[21];
  const float* bnf_b  = (const float*)d_in[22];
  const float* bnf_m  = (const float*)d_in[23];
  const float* bnf_v  = (const float*)d_in[24];
  const float* ws1    = (const float*)d_in[25];
  const float* bs1    = (const float*)d_in[26];
  const float* bns1_g = (const float*)d_in[27];
  const float* bns1_b = (const float*)d_in[28];
  const float* bns1_m = (const float*)d_in[29];
  const float* bns1_v = (const float*)d_in[30];
  const float* ws2    = (const float*)d_in[31];
  const float* bs2    = (const float*)d_in[32];
  const float* bns2_g = (const float*)d_in[33];
  const float* bns2_b = (const float*)d_in[34];
  const float* bns2_m = (const float*)d_in[35];
  const float* bns2_v = (const float*)d_in[36];
  float* out = (float*)d_out;

  float* ws = (float*)d_ws;
  size_t off = 0;
  auto alloc  = [&](size_t n) { float* p = ws + off; off += (n + 63) & ~(size_t)63; return p; };
  auto allocH = [&](size_t n) { return (unsigned short*)alloc((n + 1) / 2); };

  // ---- fixed: bf16 weights + reductions ----
  unsigned short* w2b  = allocH(128 * 128);
  unsigned short* wqvb = allocH(4 * 256 * 128);          // [wqk_i ; wv_i]
  unsigned short* wtb  = allocH(4 * 128 * 128);
  unsigned short* wfb  = allocH((size_t)F_ * 512);
  unsigned short* ws1b = allocH((size_t)H1_ * 1024);
  unsigned short* ws2b = allocH((size_t)128 * 512);      // padded to 128 rows
  float* lwB  = alloc((size_t)16 * 2048);
  float* pmax = alloc((size_t)16 * 16 * 1024);
  float* psum = alloc((size_t)16 * 16 * 1024);
  float* xmaxB = alloc((size_t)16 * 1024);
  float* xavgB = alloc((size_t)16 * 1024);
  float* ptB   = alloc((size_t)16 * 512);
  size_t fixedOff = off;

  const size_t perB = 262144 /*h1*/ + 1048576 /*feats*/ +
                      131072 /*h1b*/ + 524288 /*featsb|hs1b*/ + 1048576 /*fusedb*/ +
                      131072 /*xkb*/ + 131072 /*xvb*/ + 131072 /*xrb|h0b*/;
  size_t wsFloats = ws_size / 4;
  int Gb = 1;
  for (int c : {16, 8, 4, 2, 1}) {
    if (fixedOff + (size_t)c * perB + 4096 <= wsFloats) { Gb = c; break; }
  }

  float* h1    = alloc((size_t)Gb * 262144);
  float* feats = alloc((size_t)Gb * 1048576);
  unsigned short* h1b    = allocH((size_t)Gb * 262144);
  unsigned short* featsb = allocH((size_t)Gb * 1048576);   // hs1b aliases
  unsigned short* fusedb = allocH((size_t)Gb * 2097152);
  unsigned short* xkb    = allocH((size_t)Gb * 262144);
  unsigned short* xvb    = allocH((size_t)Gb * 262144);
  unsigned short* xrb    = allocH((size_t)Gb * 262144);    // h0b aliases
  unsigned short* h0b  = xrb;
  unsigned short* hs1b = featsb;

  // ---- one-time weight casts ----
  cast2d_k<<<64, 256, 0, stream>>>(w2, w2b, 128, 128, 128);
  for (int i = 0; i < 4; ++i) {
    cast2d_k<<<64, 256, 0, stream>>>(sa_wqk + (size_t)i * 16384, wqvb + (size_t)i * 32768, 128, 128, 128);
    cast2d_k<<<64, 256, 0, stream>>>(sa_wv  + (size_t)i * 16384, wqvb + (size_t)i * 32768 + 16384, 128, 128, 128);
    cast2d_k<<<64, 256, 0, stream>>>(sa_wt  + (size_t)i * 16384, wtb  + (size_t)i * 16384, 128, 128, 128);
  }
  cast2d_k<<<2048, 256, 0, stream>>>(wf,  wfb,  1024, 512, 512);
  cast2d_k<<<2048, 256, 0, stream>>>(ws1, ws1b, 512, 1024, 3072);
  cast2d_k<<<100,  256, 0, stream>>>(ws2, ws2b, 50, 512, 512);

  const long sAct = 262144, sFeat = 1048576, sFus = 2097152;
  for (int b0 = 0; b0 < B_; b0 += Gb) {
    int g = Gb;
    conv1_k<<<dim3(N_, g), 128, 0, stream>>>(x + (long)b0 * 3 * N_, w1,
                                             bn1_g, bn1_b, bn1_m, bn1_v, h0b);
    // conv2 + bn2 + relu -> h1 fp32 + h1b bf16
    gemm_bf<<<dim3(16, 1, g), 256, 0, stream>>>(
        w2b, 128, h0b, sAct, 128, nullptr, nullptr, nullptr, 0,
        bn2_g, bn2_b, bn2_m, bn2_v, nullptr, 0, 0,
        h1, sAct, 128, h1b, sAct, 128, nullptr, 0, 0,
        nullptr, nullptr, 128, 128, 1, 1 | 4);

    for (int i = 0; i < 4; ++i) {
      const unsigned short* lib = (i == 0) ? h1b : featsb + (size_t)(i - 1) * 128;
      const float* liF = (i == 0) ? h1 : feats + (size_t)(i - 1) * 128;
      int ldLi = (i == 0) ? 128 : 512;
      long sLi = (i == 0) ? sAct : sFeat;
      // xk (token bf16) + xv (channel bf16, +bv)
      gemm_bf<<<dim3(16, 2, g), 256, 0, stream>>>(
          wqvb + (size_t)i * 32768, 128, lib, sLi, ldLi,
          nullptr, sa_bv + i * 128, nullptr, 0,
          nullptr, nullptr, nullptr, nullptr, nullptr, 0, 0,
          nullptr, 0, 0, xkb, sAct, 128, xvb, sAct, 2048,
          nullptr, nullptr, 128, 256, 0, 64);
      gram_lw<<<dim3(32, g), 256, 0, stream>>>(xkb, sAct, lwB);
      pv_k<<<dim3(32, g), 256, 0, stream>>>(xkb, sAct, xvb, sAct, lwB,
                                            liF, sLi, ldLi, xrb, sAct);
      // feats_i = li + relu(bn(wt @ (li - xr) + bt))
      gemm_bf<<<dim3(16, 1, g), 256, 0, stream>>>(
          wtb + (size_t)i * 16384, 128, xrb, sAct, 128,
          sa_bt + i * 128, nullptr, nullptr, 0,
          sa_g + i * 128, sa_b + i * 128, sa_m + i * 128, sa_v + i * 128,
          liF, sLi, ldLi,
          feats + (size_t)i * 128, sFeat, 512,
          featsb + (size_t)i * 128, sFeat, 512, nullptr, 0, 0,
          nullptr, nullptr, 128, 128, 1, 1 | 4 | 16);
    }

    // fused = leaky(bn(wf @ feats)) -> bf16 + pool partials
    gemm_bf<<<dim3(16, 8, g), 256, 0, stream>>>(
        wfb, 512, featsb, sFeat, 512, nullptr, nullptr, nullptr, 0,
        bnf_g, bnf_b, bnf_m, bnf_v, nullptr, 0, 0,
        nullptr, 0, 0, fusedb, sFus, 1024, nullptr, 0, 0,
        pmax, psum, 512, 1024, 2, 4 | 32);
    poolred_k<<<dim3(4, g), 256, 0, stream>>>(pmax, psum, xmaxB, xavgB);
    poolterm_k<<<dim3(512, g), 256, 0, stream>>>(ws1, xmaxB, xavgB, ptB);
    // hs1 = relu(bn(ws1 @ [fused;pool] + bs1)) -> bf16
    gemm_bf<<<dim3(16, 4, g), 256, 0, stream>>>(
        ws1b, 1024, fusedb, sFus, 1024, bs1, nullptr, ptB, 512,
        bns1_g, bns1_b, bns1_m, bns1_v, nullptr, 0, 0,
        nullptr, 0, 0, hs1b, sFeat, 512, nullptr, 0, 0,
        nullptr, nullptr, 1024, 512, 1, 4);
    // out = relu(bn(ws2 @ hs1 + bs2)) -> fp32 channel-major
    gemm_bf<<<dim3(16, 1, g), 256, 0, stream>>>(
        ws2b, 512, hs1b, sFeat, 512, bs2, nullptr, nullptr, 0,
        bns2_g, bns2_b, bns2_m, bns2_v, nullptr, 0, 0,
        out + (long)b0 * OUT_ * N_, (long)OUT_ * N_, 2048,
        nullptr, 0, 0, nullptr, 0, 0,
        nullptr, nullptr, 512, 50, 1, 2);
  }
}

// Round 6
// 1045.460 us; speedup vs baseline: 1.2373x; 1.2373x over previous
//
#include <hip/hip_runtime.h>
#include <cstdint>
#include <cstddef>

#define B_   16
#define N_   2048
#define D_   128
#define F_   1024
#define H1_  512
#define OUT_ 50

static constexpr float BN_EPS = 1e-5f;

typedef __attribute__((ext_vector_type(8))) short short8;
typedef __attribute__((ext_vector_type(4))) float f32x4;

__device__ inline unsigned short f2bf(float f) {
  union { float f; unsigned u; } v; v.f = f;
  unsigned r = v.u + 0x7fff + ((v.u >> 16) & 1);
  return (unsigned short)(r >> 16);
}

// async global->LDS, 16B per lane; LDS dest = wave-uniform base + lane*16
__device__ inline void dma16(const unsigned short* g, unsigned short* l) {
  __builtin_amdgcn_global_load_lds(
      (const __attribute__((address_space(1))) unsigned int*)g,
      (__attribute__((address_space(3))) unsigned int*)l, 16, 0, 0);
}

// ---------------------------------------------------------------------------
__global__ void cast2d_k(const float* __restrict__ src, unsigned short* __restrict__ dst,
                         int R, int C, int ldSrc) {
  long i = (long)blockIdx.x * 256 + threadIdx.x;
  if (i >= (long)R * C) return;
  int r = (int)(i / C), c = (int)(i % C);
  dst[i] = f2bf(src[(long)r * ldSrc + c]);
}

// ---------------------------------------------------------------------------
// conv1 (3->128) + bn + relu -> bf16 token-major. grid (N, g), block 128
// ---------------------------------------------------------------------------
__global__ void conv1_k(const float* __restrict__ x, const float* __restrict__ w1,
                        const float* __restrict__ g, const float* __restrict__ bb,
                        const float* __restrict__ m, const float* __restrict__ v,
                        unsigned short* __restrict__ h0b) {
  int o = threadIdx.x, n = blockIdx.x, b = blockIdx.y;
  const float* xb = x + (long)b * 3 * N_;
  float val = w1[o * 3 + 0] * xb[n] + w1[o * 3 + 1] * xb[N_ + n] + w1[o * 3 + 2] * xb[2 * N_ + n];
  float sc = g[o] * rsqrtf(v[o] + BN_EPS);
  val = val * sc + (bb[o] - m[o] * sc);
  h0b[((long)b * N_ + n) * D_ + o] = f2bf(fmaxf(val, 0.f));
}

// ---------------------------------------------------------------------------
// bf16 MFMA GEMM. out[n][o] = epi( sum_k A[n][k]*W[o][k] )
// A bf16 token-major (ldA), W bf16 [O][K] (ldW). DMA staging, XOR swizzle.
// Tile 128x128, BK=64, block 256 (2x2 waves).
// flags: 1 outF token fp32 | 2 outF channel fp32 | 4 outH token bf16 |
//        16 add res (fp32 token) after act | 32 pool partials | 64 kv-split |
//        128 swapped operand order (token-major outputs -> vector stores)
// Swapped: D rows = o (quad*4+r), cols = n (l15); per-lane 4 consecutive o.
// ---------------------------------------------------------------------------
__global__ __launch_bounds__(256)
void gemm_bf(const unsigned short* __restrict__ Wb, int ldW,
             const unsigned short* __restrict__ A, long sA, int ldA,
             const float* __restrict__ bias, const float* __restrict__ bias2,
             const float* __restrict__ perBO, int ldPBO,
             const float* __restrict__ bng, const float* __restrict__ bnb,
             const float* __restrict__ bnm, const float* __restrict__ bnv,
             const float* __restrict__ res, long sRes, int ldRes,
             float* __restrict__ outF, long sOutF, int ldOutF,
             unsigned short* __restrict__ outH, long sOutH, int ldOutH,
             unsigned short* __restrict__ outH2, long sOutH2, int ldOutH2,
             float* __restrict__ pmax, float* __restrict__ psum,
             int K, int O, int act, int flags) {
  __shared__ unsigned short lAB[16384];       // lA = [0..8191], lB = [8192..]
  __shared__ float lpm[4][64], lps[4][64];
  unsigned short* lA = lAB;
  unsigned short* lB = lAB + 8192;
  int tid = threadIdx.x;
  int n0 = blockIdx.x * 128, o0 = blockIdx.y * 128, b = blockIdx.z;
  int wave = tid >> 6, lane = tid & 63;
  int wr = wave >> 1, wc = wave & 1;
  int quad = lane >> 4, l15 = lane & 15;
  int rowL = lane >> 3;
  int kseg = (lane & 7) ^ rowL;
  const unsigned short* Ab = A + (long)b * sA + (long)n0 * ldA;
  const unsigned short* Wp = Wb + (long)o0 * ldW;
  bool swapped = ((flags & 128) != 0) || (((flags & 64) != 0) && o0 < 128);

  f32x4 acc[4][4];
  #pragma unroll
  for (int i = 0; i < 4; ++i)
    #pragma unroll
    for (int j = 0; j < 4; ++j) acc[i][j] = (f32x4){0.f, 0.f, 0.f, 0.f};

  for (int kc = 0; kc < K; kc += 64) {
    #pragma unroll
    for (int t = 0; t < 4; ++t) {
      int chunk = t * 4 + wave;
      int row = chunk * 8 + rowL;
      dma16(Ab + (long)row * ldA + kc + kseg * 8, &lA[chunk * 512]);
      dma16(Wp + (long)row * ldW + kc + kseg * 8, &lB[chunk * 512]);
    }
    __syncthreads();
    #pragma unroll
    for (int kk = 0; kk < 2; ++kk) {
      short8 af[4], bf[4];
      #pragma unroll
      for (int mt = 0; mt < 4; ++mt) {
        int r = wr * 64 + mt * 16 + l15;
        af[mt] = *(const short8*)&lA[r * 64 + (((kk * 4 + quad) ^ (l15 & 7)) * 8)];
      }
      #pragma unroll
      for (int ot = 0; ot < 4; ++ot) {
        int r = wc * 64 + ot * 16 + l15;
        bf[ot] = *(const short8*)&lB[r * 64 + (((kk * 4 + quad) ^ (l15 & 7)) * 8)];
      }
      if (swapped) {
        #pragma unroll
        for (int mt = 0; mt < 4; ++mt)
          #pragma unroll
          for (int ot = 0; ot < 4; ++ot)
            acc[mt][ot] = __builtin_amdgcn_mfma_f32_16x16x32_bf16(bf[ot], af[mt], acc[mt][ot], 0, 0, 0);
      } else {
        #pragma unroll
        for (int mt = 0; mt < 4; ++mt)
          #pragma unroll
          for (int ot = 0; ot < 4; ++ot)
            acc[mt][ot] = __builtin_amdgcn_mfma_f32_16x16x32_bf16(af[mt], bf[ot], acc[mt][ot], 0, 0, 0);
      }
    }
    __syncthreads();
  }

  if (!swapped) {
    // channel-major outputs: ws2 fp32 [o][n] (flags&2) or xv bf16 [d][n] (kv)
    bool isV = (flags & 64) && (o0 >= 128);
    #pragma unroll
    for (int ot = 0; ot < 4; ++ot) {
      int o = o0 + wc * 64 + ot * 16 + l15;
      if (o >= O) continue;
      float bi = 0.f, sc = 1.f, sh = 0.f;
      if (isV) { bi = bias2[o - 128]; }
      else if (bias) bi = bias[o];
      if (perBO) bi += perBO[(long)b * ldPBO + o];
      if (bng) { sc = bng[o] * rsqrtf(bnv[o] + BN_EPS); sh = bnb[o] - bnm[o] * sc; }
      #pragma unroll
      for (int mt = 0; mt < 4; ++mt) {
        int nb = n0 + wr * 64 + mt * 16 + quad * 4;
        float vals[4];
        #pragma unroll
        for (int r = 0; r < 4; ++r) {
          float val = acc[mt][ot][r] + bi;
          val = val * sc + sh;
          if (act == 1)      val = fmaxf(val, 0.f);
          else if (act == 2) val = (val >= 0.f) ? val : 0.2f * val;
          vals[r] = val;
        }
        if (isV) {
          unsigned short t[4];
          #pragma unroll
          for (int r = 0; r < 4; ++r) t[r] = f2bf(vals[r]);
          *(uint2*)&outH2[(long)b * sOutH2 + (long)(o - 128) * ldOutH2 + nb] = *(uint2*)&t[0];
        } else {
          *(float4*)&outF[(long)b * sOutF + (long)o * ldOutF + nb] = *(float4*)vals;
        }
      }
    }
    return;
  }

  // swapped epilogue: lane holds o = ob..ob+3 (consecutive), n = per-mt fixed
  bool doPool = (flags & 32) != 0;
  bool isK = (flags & 64) != 0;      // xk path: no bias/bn
  #pragma unroll
  for (int ot = 0; ot < 4; ++ot) {
    int ob = o0 + wc * 64 + ot * 16 + quad * 4;
    float bi[4] = {0.f, 0.f, 0.f, 0.f}, sc[4] = {1.f, 1.f, 1.f, 1.f}, sh[4] = {0.f, 0.f, 0.f, 0.f};
    if (!isK) {
      if (bias) { float4 t = *(const float4*)&bias[ob]; bi[0] = t.x; bi[1] = t.y; bi[2] = t.z; bi[3] = t.w; }
      if (perBO) {
        float4 t = *(const float4*)&perBO[(long)b * ldPBO + ob];
        bi[0] += t.x; bi[1] += t.y; bi[2] += t.z; bi[3] += t.w;
      }
      if (bng) {
        float4 g4 = *(const float4*)&bng[ob];
        float4 v4 = *(const float4*)&bnv[ob];
        float4 b4 = *(const float4*)&bnb[ob];
        float4 m4 = *(const float4*)&bnm[ob];
        float gg[4] = {g4.x, g4.y, g4.z, g4.w}, vv[4] = {v4.x, v4.y, v4.z, v4.w};
        float bb4[4] = {b4.x, b4.y, b4.z, b4.w}, mm[4] = {m4.x, m4.y, m4.z, m4.w};
        #pragma unroll
        for (int r = 0; r < 4; ++r) { sc[r] = gg[r] * rsqrtf(vv[r] + BN_EPS); sh[r] = bb4[r] - mm[r] * sc[r]; }
      }
    }
    float pm4[4], ps4[4];
    #pragma unroll
    for (int r = 0; r < 4; ++r) { pm4[r] = -1e30f; ps4[r] = 0.f; }
    #pragma unroll
    for (int mt = 0; mt < 4; ++mt) {
      int n = n0 + wr * 64 + mt * 16 + l15;
      float vals[4];
      #pragma unroll
      for (int r = 0; r < 4; ++r) {
        float val = acc[mt][ot][r] + bi[r];
        val = val * sc[r] + sh[r];
        if (act == 1)      val = fmaxf(val, 0.f);
        else if (act == 2) val = (val >= 0.f) ? val : 0.2f * val;
        vals[r] = val;
      }
      if (flags & 16) {
        float4 t = *(const float4*)&res[(long)b * sRes + (long)n * ldRes + ob];
        vals[0] += t.x; vals[1] += t.y; vals[2] += t.z; vals[3] += t.w;
      }
      if (flags & 1)
        *(float4*)&outF[(long)b * sOutF + (long)n * ldOutF + ob] = *(float4*)vals;
      {
        unsigned short t[4];
        #pragma unroll
        for (int r = 0; r < 4; ++r) t[r] = f2bf(vals[r]);
        *(uint2*)&outH[(long)b * sOutH + (long)n * ldOutH + ob] = *(uint2*)&t[0];
      }
      if (doPool) {
        #pragma unroll
        for (int r = 0; r < 4; ++r) { pm4[r] = fmaxf(pm4[r], vals[r]); ps4[r] += vals[r]; }
      }
    }
    if (doPool) {
      #pragma unroll
      for (int r = 0; r < 4; ++r) {
        float m = pm4[r], s = ps4[r];
        m = fmaxf(m, __shfl_xor(m, 1)); s += __shfl_xor(s, 1);
        m = fmaxf(m, __shfl_xor(m, 2)); s += __shfl_xor(s, 2);
        m = fmaxf(m, __shfl_xor(m, 4)); s += __shfl_xor(s, 4);
        m = fmaxf(m, __shfl_xor(m, 8)); s += __shfl_xor(s, 8);
        if (l15 == 0) { lpm[wave][ot * 16 + quad * 4 + r] = m; lps[wave][ot * 16 + quad * 4 + r] = s; }
      }
    }
  }
  if (doPool) {
    __syncthreads();
    if (tid < 128) {
      int wcx = tid >> 6, ol = tid & 63;
      float m = fmaxf(lpm[wcx][ol], lpm[wcx + 2][ol]);
      float s = lps[wcx][ol] + lps[wcx + 2][ol];
      int o = o0 + wcx * 64 + ol;
      pmax[((long)b * 16 + blockIdx.x) * 1024 + o] = m;
      psum[((long)b * 16 + blockIdx.x) * 1024 + o] = s;
    }
  }
}

// ---------------------------------------------------------------------------
// Gram row-stats -> lw[n] = mx[n] + log(rs[n]).  E = xk xk^T, K=128.
// xk bf16 token [2048][128]; DMA-staged swizzled LDS. grid (32, g), block 256.
// ---------------------------------------------------------------------------
__global__ __launch_bounds__(256)
void gram_lw(const unsigned short* __restrict__ xk, long sXk,
             float* __restrict__ lw) {
  __shared__ unsigned short lK[64 * 128];   // 16KB, 16-seg swizzle
  int tid = threadIdx.x, wave = tid >> 6, lane = tid & 63;
  int quad = lane >> 4, l15 = lane & 15;
  int rowL4 = lane >> 4, s16 = lane & 15;
  int n0 = blockIdx.x * 64, b = blockIdx.y;
  const unsigned short* Kp = xk + (long)b * sXk;
  short8 afr[4];
  {
    const unsigned short* arow = Kp + (long)(n0 + wave * 16 + l15) * 128;
    #pragma unroll
    for (int kf = 0; kf < 4; ++kf) afr[kf] = *(const short8*)(arow + kf * 32 + quad * 8);
  }
  float runm[4], runs[4];
  #pragma unroll
  for (int r = 0; r < 4; ++r) { runm[r] = -1e30f; runs[r] = 0.f; }

  for (int m0 = 0; m0 < 2048; m0 += 64) {
    __syncthreads();
    #pragma unroll
    for (int t = 0; t < 4; ++t) {
      int c = t * 4 + wave;
      int row = c * 4 + rowL4;
      int gseg = (s16 & 8) | ((s16 ^ (row & 7)) & 7);
      dma16(Kp + (long)(m0 + row) * 128 + gseg * 8, &lK[c * 512]);
    }
    __syncthreads();
    #pragma unroll
    for (int mf = 0; mf < 4; ++mf) {
      f32x4 s = (f32x4){0.f, 0.f, 0.f, 0.f};
      #pragma unroll
      for (int kf = 0; kf < 4; ++kf) {
        int r = mf * 16 + l15, q = kf * 4 + quad;
        int sp = (q & 8) | ((q ^ (r & 7)) & 7);
        short8 bfr = *(const short8*)&lK[r * 128 + sp * 8];
        s = __builtin_amdgcn_mfma_f32_16x16x32_bf16(afr[kf], bfr, s, 0, 0, 0);
      }
      #pragma unroll
      for (int r = 0; r < 4; ++r) {
        float e = s[r];
        float mn = fmaxf(runm[r], e);
        runs[r] = runs[r] * __expf(runm[r] - mn) + __expf(e - mn);
        runm[r] = mn;
      }
    }
  }
  #pragma unroll
  for (int r = 0; r < 4; ++r) {
    float m = runm[r], s = runs[r];
    #pragma unroll
    for (int off = 1; off < 16; off <<= 1) {
      float mo = __shfl_xor(m, off), so = __shfl_xor(s, off);
      float mn = fmaxf(m, mo);
      s = s * __expf(m - mn) + so * __expf(mo - mn);
      m = mn;
    }
    if (l15 == 0) {
      int n = n0 + wave * 16 + quad * 4 + r;
      lw[(long)b * 2048 + n] = m + __logf(s);
    }
  }
}

// ---------------------------------------------------------------------------
// Fused PV: p[m][n] = exp(E[m][n] - lw[n]);  cs[m] = sum_n p;
// xrb[m][d] = bf16( li[m][d] - (sum_n p[m][n]*xv[d][n]) / (1e-9+cs[m]) )
// grid (32, g), block 256.
// ---------------------------------------------------------------------------
__global__ __launch_bounds__(256)
void pv_k(const unsigned short* __restrict__ xk, long sXk,
          const unsigned short* __restrict__ xv, long sXv,
          const float* __restrict__ lw,
          const float* __restrict__ li, long sLi, int ldLi,
          unsigned short* __restrict__ xrb, long sXr) {
  __shared__ unsigned short lK[64 * 128];   // 16KB, 16-seg swizzle
  __shared__ unsigned short lV[128 * 64];   // 16KB, 8-seg swizzle
  __shared__ unsigned short lP[4][16 * 72];
  __shared__ float lwt[64];
  int tid = threadIdx.x, wave = tid >> 6, lane = tid & 63;
  int quad = lane >> 4, l15 = lane & 15;
  int rowL4 = lane >> 4, s16 = lane & 15;
  int rowL8 = lane >> 3, s8 = lane & 7;
  int m0 = blockIdx.x * 64, b = blockIdx.y;
  const unsigned short* Kp = xk + (long)b * sXk;
  const unsigned short* Vp = xv + (long)b * sXv;
  short8 akr[4];
  {
    const unsigned short* arow = Kp + (long)(m0 + wave * 16 + l15) * 128;
    #pragma unroll
    for (int kf = 0; kf < 4; ++kf) akr[kf] = *(const short8*)(arow + kf * 32 + quad * 8);
  }
  f32x4 acc[8];
  #pragma unroll
  for (int dt = 0; dt < 8; ++dt) acc[dt] = (f32x4){0.f, 0.f, 0.f, 0.f};
  float runc[4] = {0.f, 0.f, 0.f, 0.f};

  for (int n0c = 0; n0c < 2048; n0c += 64) {
    __syncthreads();
    #pragma unroll
    for (int t = 0; t < 4; ++t) {
      int cK = t * 4 + wave;
      int rowK = cK * 4 + rowL4;
      int gsegK = (s16 & 8) | ((s16 ^ (rowK & 7)) & 7);
      dma16(Kp + (long)(n0c + rowK) * 128 + gsegK * 8, &lK[cK * 512]);
      int cV = t * 4 + wave;
      int rowV = cV * 8 + rowL8;
      int gsegV = s8 ^ (rowV & 7);
      dma16(Vp + (long)rowV * 2048 + n0c + gsegV * 8, &lV[cV * 512]);
    }
    if (tid < 64) lwt[tid] = lw[(long)b * 2048 + n0c + tid];
    __syncthreads();
    #pragma unroll
    for (int nf = 0; nf < 4; ++nf) {
      f32x4 s = (f32x4){0.f, 0.f, 0.f, 0.f};
      #pragma unroll
      for (int kf = 0; kf < 4; ++kf) {
        int r = nf * 16 + l15, q = kf * 4 + quad;
        int sp = (q & 8) | ((q ^ (r & 7)) & 7);
        short8 bfr = *(const short8*)&lK[r * 128 + sp * 8];
        s = __builtin_amdgcn_mfma_f32_16x16x32_bf16(akr[kf], bfr, s, 0, 0, 0);
      }
      float lwc = lwt[nf * 16 + l15];
      #pragma unroll
      for (int r = 0; r < 4; ++r) {
        float p = __expf(s[r] - lwc);
        runc[r] += p;
        lP[wave][(quad * 4 + r) * 72 + nf * 16 + l15] = f2bf(p);
      }
    }
    __syncthreads();
    #pragma unroll
    for (int kc = 0; kc < 2; ++kc) {
      short8 pa = *(const short8*)&lP[wave][l15 * 72 + kc * 32 + quad * 8];
      #pragma unroll
      for (int dt = 0; dt < 8; ++dt) {
        int r = dt * 16 + l15, q = kc * 4 + quad;
        int sp = q ^ (r & 7);
        short8 vb = *(const short8*)&lV[r * 64 + sp * 8];
        acc[dt] = __builtin_amdgcn_mfma_f32_16x16x32_bf16(pa, vb, acc[dt], 0, 0, 0);
      }
    }
  }
  float inv[4];
  #pragma unroll
  for (int r = 0; r < 4; ++r) {
    float s = runc[r];
    #pragma unroll
    for (int off = 1; off < 16; off <<= 1) s += __shfl_xor(s, off);
    inv[r] = 1.f / (1e-9f + s);
  }
  #pragma unroll
  for (int dt = 0; dt < 8; ++dt) {
    int d = dt * 16 + l15;
    #pragma unroll
    for (int r = 0; r < 4; ++r) {
      int m = m0 + wave * 16 + quad * 4 + r;
      float lv = li[(long)b * sLi + (long)m * ldLi + d];
      xrb[(long)b * sXr + (long)m * 128 + d] = f2bf(lv - acc[dt][r] * inv[r]);
    }
  }
}

// ---------------------------------------------------------------------------
__global__ void poolred_k(const float* __restrict__ pmax, const float* __restrict__ psum,
                          float* __restrict__ xmax, float* __restrict__ xavg) {
  int f = blockIdx.x * 256 + threadIdx.x, b = blockIdx.y;
  float mx = -1e30f, s = 0.f;
  #pragma unroll
  for (int t = 0; t < 16; ++t) {
    mx = fmaxf(mx, pmax[((long)b * 16 + t) * 1024 + f]);
    s += psum[((long)b * 16 + t) * 1024 + f];
  }
  xmax[(long)b * 1024 + f] = mx;
  xavg[(long)b * 1024 + f] = s * (1.f / 2048.f);
}

__global__ __launch_bounds__(256)
void poolterm_k(const float* __restrict__ ws1, const float* __restrict__ xmax,
                const float* __restrict__ xavg, float* __restrict__ pt) {
  int o = blockIdx.x, b = blockIdx.y, tid = threadIdx.x;
  const float* w = ws1 + (long)o * 3072;
  float s = 0.f;
  #pragma unroll
  for (int it = 0; it < 4; ++it) {
    int c = tid + it * 256;
    s += w[1024 + c] * xmax[(long)b * 1024 + c] + w[2048 + c] * xavg[(long)b * 1024 + c];
  }
  #pragma unroll
  for (int off = 32; off; off >>= 1) s += __shfl_xor(s, off);
  __shared__ float rsm[4];
  if ((tid & 63) == 0) rsm[tid >> 6] = s;
  __syncthreads();
  if (tid == 0) pt[(long)b * H1_ + o] = rsm[0] + rsm[1] + rsm[2] + rsm[3];
}

// ---------------------------------------------------------------------------
extern "C" void kernel_launch(void* const* d_in, const int* in_sizes, int n_in,
                              void* d_out, int out_size, void* d_ws, size_t ws_size,
                              hipStream_t stream) {
  const float* x      = (const float*)d_in[0];
  const float* w1     = (const float*)d_in[1];
  const float* w2     = (const float*)d_in[2];
  const float* bn1_g  = (const float*)d_in[3];
  const float* bn1_b  = (const float*)d_in[4];
  const float* bn1_m  = (const float*)d_in[5];
  const float* bn1_v  = (const float*)d_in[6];
  const float* bn2_g  = (const float*)d_in[7];
  const float* bn2_b  = (const float*)d_in[8];
  const float* bn2_m  = (const float*)d_in[9];
  const float* bn2_v  = (const float*)d_in[10];
  const float* sa_wqk = (const float*)d_in[11];
  const float* sa_wv  = (const float*)d_in[12];
  const float* sa_bv  = (const float*)d_in[13];
  const float* sa_wt  = (const float*)d_in[14];
  const float* sa_bt  = (const float*)d_in[15];
  const float* sa_g   = (const float*)d_in[16];
  const float* sa_b   = (const float*)d_in[17];
  const float* sa_m   = (const float*)d_in[18];
  const float* sa_v   = (const float*)d_in[19];
  const float* wf     = (const float*)d_in[20];
  const float* bnf_g  = (const float*)d_in[21];
  const float* bnf_b  = (const float*)d_in[22];
  const float* bnf_m  = (const float*)d_in[23];
  const float* bnf_v  = (const float*)d_in[24];
  const float* ws1    = (const float*)d_in[25];
  const float* bs1    = (const float*)d_in[26];
  const float* bns1_g = (const float*)d_in[27];
  const float* bns1_b = (const float*)d_in[28];
  const float* bns1_m = (const float*)d_in[29];
  const float* bns1_v = (const float*)d_in[30];
  const float* ws2    = (const float*)d_in[31];
  const float* bs2    = (const float*)d_in[32];
  const float* bns2_g = (const float*)d_in[33];
  const float* bns2_b = (const float*)d_in[34];
  const float* bns2_m = (const float*)d_in[35];
  const float* bns2_v = (const float*)d_in[36];
  float* out = (float*)d_out;

  float* ws = (float*)d_ws;
  size_t off = 0;
  auto alloc  = [&](size_t n) { float* p = ws + off; off += (n + 63) & ~(size_t)63; return p; };
  auto allocH = [&](size_t n) { return (unsigned short*)alloc((n + 1) / 2); };

  // ---- fixed: bf16 weights + reductions ----
  unsigned short* w2b  = allocH(128 * 128);
  unsigned short* wqvb = allocH(4 * 256 * 128);          // [wqk_i ; wv_i]
  unsigned short* wtb  = allocH(4 * 128 * 128);
  unsigned short* wfb  = allocH((size_t)F_ * 512);
  unsigned short* ws1b = allocH((size_t)H1_ * 1024);
  unsigned short* ws2b = allocH((size_t)128 * 512);      // padded to 128 rows
  float* lwB  = alloc((size_t)16 * 2048);
  float* pmax = alloc((size_t)16 * 16 * 1024);
  float* psum = alloc((size_t)16 * 16 * 1024);
  float* xmaxB = alloc((size_t)16 * 1024);
  float* xavgB = alloc((size_t)16 * 1024);
  float* ptB   = alloc((size_t)16 * 512);
  size_t fixedOff = off;

  const size_t perB = 262144 /*h1*/ + 1048576 /*feats*/ +
                      131072 /*h1b*/ + 524288 /*featsb|hs1b*/ + 1048576 /*fusedb*/ +
                      131072 /*xkb*/ + 131072 /*xvb*/ + 131072 /*xrb|h0b*/;
  size_t wsFloats = ws_size / 4;
  int Gb = 1;
  for (int c : {16, 8, 4, 2, 1}) {
    if (fixedOff + (size_t)c * perB + 4096 <= wsFloats) { Gb = c; break; }
  }

  float* h1    = alloc((size_t)Gb * 262144);
  float* feats = alloc((size_t)Gb * 1048576);
  unsigned short* h1b    = allocH((size_t)Gb * 262144);
  unsigned short* featsb = allocH((size_t)Gb * 1048576);   // hs1b aliases
  unsigned short* fusedb = allocH((size_t)Gb * 2097152);
  unsigned short* xkb    = allocH((size_t)Gb * 262144);
  unsigned short* xvb    = allocH((size_t)Gb * 262144);
  unsigned short* xrb    = allocH((size_t)Gb * 262144);    // h0b aliases
  unsigned short* h0b  = xrb;
  unsigned short* hs1b = featsb;

  // ---- one-time weight casts ----
  cast2d_k<<<64, 256, 0, stream>>>(w2, w2b, 128, 128, 128);
  for (int i = 0; i < 4; ++i) {
    cast2d_k<<<64, 256, 0, stream>>>(sa_wqk + (size_t)i * 16384, wqvb + (size_t)i * 32768, 128, 128, 128);
    cast2d_k<<<64, 256, 0, stream>>>(sa_wv  + (size_t)i * 16384, wqvb + (size_t)i * 32768 + 16384, 128, 128, 128);
    cast2d_k<<<64, 256, 0, stream>>>(sa_wt  + (size_t)i * 16384, wtb  + (size_t)i * 16384, 128, 128, 128);
  }
  cast2d_k<<<2048, 256, 0, stream>>>(wf,  wfb,  1024, 512, 512);
  cast2d_k<<<2048, 256, 0, stream>>>(ws1, ws1b, 512, 1024, 3072);
  cast2d_k<<<100,  256, 0, stream>>>(ws2, ws2b, 50, 512, 512);

  const long sAct = 262144, sFeat = 1048576, sFus = 2097152;
  for (int b0 = 0; b0 < B_; b0 += Gb) {
    int g = Gb;
    conv1_k<<<dim3(N_, g), 128, 0, stream>>>(x + (long)b0 * 3 * N_, w1,
                                             bn1_g, bn1_b, bn1_m, bn1_v, h0b);
    // conv2 + bn2 + relu -> h1 fp32 + h1b bf16  (swapped, vector stores)
    gemm_bf<<<dim3(16, 1, g), 256, 0, stream>>>(
        w2b, 128, h0b, sAct, 128, nullptr, nullptr, nullptr, 0,
        bn2_g, bn2_b, bn2_m, bn2_v, nullptr, 0, 0,
        h1, sAct, 128, h1b, sAct, 128, nullptr, 0, 0,
        nullptr, nullptr, 128, 128, 1, 1 | 4 | 128);

    for (int i = 0; i < 4; ++i) {
      const unsigned short* lib = (i == 0) ? h1b : featsb + (size_t)(i - 1) * 128;
      const float* liF = (i == 0) ? h1 : feats + (size_t)(i - 1) * 128;
      int ldLi = (i == 0) ? 128 : 512;
      long sLi = (i == 0) ? sAct : sFeat;
      // xk (token bf16, swapped) + xv (channel bf16, +bv)
      gemm_bf<<<dim3(16, 2, g), 256, 0, stream>>>(
          wqvb + (size_t)i * 32768, 128, lib, sLi, ldLi,
          nullptr, sa_bv + i * 128, nullptr, 0,
          nullptr, nullptr, nullptr, nullptr, nullptr, 0, 0,
          nullptr, 0, 0, xkb, sAct, 128, xvb, sAct, 2048,
          nullptr, nullptr, 128, 256, 0, 64);
      gram_lw<<<dim3(32, g), 256, 0, stream>>>(xkb, sAct, lwB);
      pv_k<<<dim3(32, g), 256, 0, stream>>>(xkb, sAct, xvb, sAct, lwB,
                                            liF, sLi, ldLi, xrb, sAct);
      // feats_i = li + relu(bn(wt @ (li - xr) + bt))  (swapped)
      gemm_bf<<<dim3(16, 1, g), 256, 0, stream>>>(
          wtb + (size_t)i * 16384, 128, xrb, sAct, 128,
          sa_bt + i * 128, nullptr, nullptr, 0,
          sa_g + i * 128, sa_b + i * 128, sa_m + i * 128, sa_v + i * 128,
          liF, sLi, ldLi,
          feats + (size_t)i * 128, sFeat, 512,
          featsb + (size_t)i * 128, sFeat, 512, nullptr, 0, 0,
          nullptr, nullptr, 128, 128, 1, 1 | 4 | 16 | 128);
    }

    // fused = leaky(bn(wf @ feats)) -> bf16 + pool partials  (swapped)
    gemm_bf<<<dim3(16, 8, g), 256, 0, stream>>>(
        wfb, 512, featsb, sFeat, 512, nullptr, nullptr, nullptr, 0,
        bnf_g, bnf_b, bnf_m, bnf_v, nullptr, 0, 0,
        nullptr, 0, 0, fusedb, sFus, 1024, nullptr, 0, 0,
        pmax, psum, 512, 1024, 2, 4 | 32 | 128);
    poolred_k<<<dim3(4, g), 256, 0, stream>>>(pmax, psum, xmaxB, xavgB);
    poolterm_k<<<dim3(512, g), 256, 0, stream>>>(ws1, xmaxB, xavgB, ptB);
    // hs1 = relu(bn(ws1 @ [fused;pool] + bs1)) -> bf16  (swapped)
    gemm_bf<<<dim3(16, 4, g), 256, 0, stream>>>(
        ws1b, 1024, fusedb, sFus, 1024, bs1, nullptr, ptB, 512,
        bns1_g, bns1_b, bns1_m, bns1_v, nullptr, 0, 0,
        nullptr, 0, 0, hs1b, sFeat, 512, nullptr, 0, 0,
        nullptr, nullptr, 1024, 512, 1, 4 | 128);
    // out = relu(bn(ws2 @ hs1 + bs2)) -> fp32 channel-major (unswapped)
    gemm_bf<<<dim3(16, 1, g), 256, 0, stream>>>(
        ws2b, 512, hs1b, sFeat, 512, bs2, nullptr, nullptr, 0,
        bns2_g, bns2_b, bns2_m, bns2_v, nullptr, 0, 0,
        out + (long)b0 * OUT_ * N_, (long)OUT_ * N_, 2048,
        nullptr, 0, 0, nullptr, 0, 0,
        nullptr, nullptr, 512, 50, 1, 2);
  }
}

// Round 7
// 849.042 us; speedup vs baseline: 1.5235x; 1.2313x over previous
//
#include <hip/hip_runtime.h>
#include <cstdint>
#include <cstddef>

#define B_   16
#define N_   2048
#define D_   128
#define F_   1024
#define H1_  512
#define OUT_ 50

static constexpr float BN_EPS = 1e-5f;

typedef __attribute__((ext_vector_type(8))) short short8;
typedef __attribute__((ext_vector_type(4))) float f32x4;

__device__ inline unsigned short f2bf(float f) {
  union { float f; unsigned u; } v; v.f = f;
  unsigned r = v.u + 0x7fff + ((v.u >> 16) & 1);
  return (unsigned short)(r >> 16);
}

// async global->LDS, 16B per lane; LDS dest = wave-uniform base + lane*16
__device__ inline void dma16(const unsigned short* g, unsigned short* l) {
  __builtin_amdgcn_global_load_lds(
      (const __attribute__((address_space(1))) unsigned int*)g,
      (__attribute__((address_space(3))) unsigned int*)l, 16, 0, 0);
}

// ---------------------------------------------------------------------------
// Fold BN (+bias) into bf16 weights + fp32 bias:
//   W'[o][k] = W[o][k]*sc[o];  b'[o] = bias[o]*sc[o] + sh[o]
// Rows O..Opad-1 zero-padded.
// ---------------------------------------------------------------------------
__global__ void foldw_k(const float* __restrict__ W, int ldW,
                        const float* __restrict__ bias,
                        const float* __restrict__ g, const float* __restrict__ bb,
                        const float* __restrict__ m, const float* __restrict__ v,
                        unsigned short* __restrict__ Wb, float* __restrict__ biasF,
                        int O, int Opad, int K) {
  long i = (long)blockIdx.x * 256 + threadIdx.x;
  if (i >= (long)Opad * K) return;
  int o = (int)(i / K), k = (int)(i % K);
  float sc = 1.f, sh = 0.f;
  if (o < O && g) { sc = g[o] * rsqrtf(v[o] + BN_EPS); sh = bb[o] - m[o] * sc; }
  float w = (o < O) ? W[(long)o * ldW + k] * sc : 0.f;
  Wb[i] = f2bf(w);
  if (k == 0 && biasF) {
    float bf = 0.f;
    if (o < O) bf = (bias ? bias[o] : 0.f) * sc + sh;
    biasF[o] = bf;
  }
}

// ---------------------------------------------------------------------------
// conv1 (3->128) + bn + relu -> bf16 token-major. grid (N, g), block 128
// ---------------------------------------------------------------------------
__global__ void conv1_k(const float* __restrict__ x, const float* __restrict__ w1,
                        const float* __restrict__ g, const float* __restrict__ bb,
                        const float* __restrict__ m, const float* __restrict__ v,
                        unsigned short* __restrict__ h0b) {
  int o = threadIdx.x, n = blockIdx.x, b = blockIdx.y;
  const float* xb = x + (long)b * 3 * N_;
  float val = w1[o * 3 + 0] * xb[n] + w1[o * 3 + 1] * xb[N_ + n] + w1[o * 3 + 2] * xb[2 * N_ + n];
  float sc = g[o] * rsqrtf(v[o] + BN_EPS);
  val = val * sc + (bb[o] - m[o] * sc);
  h0b[((long)b * N_ + n) * D_ + o] = f2bf(fmaxf(val, 0.f));
}

// ---------------------------------------------------------------------------
// Token-output MFMA GEMM (swapped operands): out[n][o], O multiple of 128.
// A bf16 token-major (ldA), W' bf16 [O][K] (BN/bias pre-folded).
// Tile TM x 128, BK=64, block 256 (2x2 waves). DMA staging + XOR swizzle.
// flags: 1 outF fp32 token | 16 add res (fp32 token) after act | 32 pool
// outH (bf16 token) always written.  act: 0 none, 1 relu, 2 leaky(0.2).
// ---------------------------------------------------------------------------
template <int TM>
__global__ __launch_bounds__(256, 4)
void gemm_tok(const unsigned short* __restrict__ Wb, int ldW,
              const unsigned short* __restrict__ A, long sA, int ldA,
              const float* __restrict__ biasF,
              const float* __restrict__ perBO, int ldPBO,
              const float* __restrict__ res, long sRes, int ldRes,
              float* __restrict__ outF, long sOutF, int ldOutF,
              unsigned short* __restrict__ outH, long sOutH, int ldOutH,
              float* __restrict__ pmax, float* __restrict__ psum,
              int K, int act, int flags) {
  constexpr int MT = TM / 32;
  __shared__ unsigned short lA[TM * 64];
  __shared__ unsigned short lB[128 * 64];
  __shared__ float lpm[4][64], lps[4][64];
  int tid = threadIdx.x;
  int n0 = blockIdx.x * TM, o0 = blockIdx.y * 128, b = blockIdx.z;
  int wave = tid >> 6, lane = tid & 63;
  int wr = wave >> 1, wc = wave & 1;
  int quad = lane >> 4, l15 = lane & 15;
  int rowL = lane >> 3;
  int kseg = (lane & 7) ^ rowL;
  const unsigned short* Ab = A + (long)b * sA + (long)n0 * ldA;
  const unsigned short* Wp = Wb + (long)o0 * ldW;

  f32x4 acc[MT][4];
  #pragma unroll
  for (int i = 0; i < MT; ++i)
    #pragma unroll
    for (int j = 0; j < 4; ++j) acc[i][j] = (f32x4){0.f, 0.f, 0.f, 0.f};

  for (int kc = 0; kc < K; kc += 64) {
    #pragma unroll
    for (int t = 0; t < 4; ++t) {
      int chunk = t * 4 + wave;
      dma16(Wp + (long)(chunk * 8 + rowL) * ldW + kc + kseg * 8, &lB[chunk * 512]);
      if (chunk < TM / 8)
        dma16(Ab + (long)(chunk * 8 + rowL) * ldA + kc + kseg * 8, &lA[chunk * 512]);
    }
    __syncthreads();
    #pragma unroll
    for (int kk = 0; kk < 2; ++kk) {
      short8 af[MT], bf[4];
      #pragma unroll
      for (int mt = 0; mt < MT; ++mt) {
        int r = wr * (TM / 2) + mt * 16 + l15;
        af[mt] = *(const short8*)&lA[r * 64 + (((kk * 4 + quad) ^ (l15 & 7)) * 8)];
      }
      #pragma unroll
      for (int ot = 0; ot < 4; ++ot) {
        int r = wc * 64 + ot * 16 + l15;
        bf[ot] = *(const short8*)&lB[r * 64 + (((kk * 4 + quad) ^ (l15 & 7)) * 8)];
      }
      #pragma unroll
      for (int mt = 0; mt < MT; ++mt)
        #pragma unroll
        for (int ot = 0; ot < 4; ++ot)
          acc[mt][ot] = __builtin_amdgcn_mfma_f32_16x16x32_bf16(bf[ot], af[mt], acc[mt][ot], 0, 0, 0);
    }
    __syncthreads();
  }

  bool doPool = (flags & 32) != 0;
  #pragma unroll
  for (int ot = 0; ot < 4; ++ot) {
    int ob = o0 + wc * 64 + ot * 16 + quad * 4;
    float bi[4] = {0.f, 0.f, 0.f, 0.f};
    if (biasF) { float4 t = *(const float4*)&biasF[ob]; bi[0] = t.x; bi[1] = t.y; bi[2] = t.z; bi[3] = t.w; }
    if (perBO) {
      float4 t = *(const float4*)&perBO[(long)b * ldPBO + ob];
      bi[0] += t.x; bi[1] += t.y; bi[2] += t.z; bi[3] += t.w;
    }
    float pm4[4], ps4[4];
    #pragma unroll
    for (int r = 0; r < 4; ++r) { pm4[r] = -1e30f; ps4[r] = 0.f; }
    #pragma unroll
    for (int mt = 0; mt < MT; ++mt) {
      int n = n0 + wr * (TM / 2) + mt * 16 + l15;
      float vals[4];
      #pragma unroll
      for (int r = 0; r < 4; ++r) {
        float val = acc[mt][ot][r] + bi[r];
        if (act == 1)      val = fmaxf(val, 0.f);
        else if (act == 2) val = (val >= 0.f) ? val : 0.2f * val;
        vals[r] = val;
      }
      if (flags & 16) {
        float4 t = *(const float4*)&res[(long)b * sRes + (long)n * ldRes + ob];
        vals[0] += t.x; vals[1] += t.y; vals[2] += t.z; vals[3] += t.w;
      }
      if (flags & 1)
        *(float4*)&outF[(long)b * sOutF + (long)n * ldOutF + ob] = *(float4*)vals;
      {
        unsigned short t[4];
        #pragma unroll
        for (int r = 0; r < 4; ++r) t[r] = f2bf(vals[r]);
        *(uint2*)&outH[(long)b * sOutH + (long)n * ldOutH + ob] = *(uint2*)&t[0];
      }
      if (doPool) {
        #pragma unroll
        for (int r = 0; r < 4; ++r) { pm4[r] = fmaxf(pm4[r], vals[r]); ps4[r] += vals[r]; }
      }
    }
    if (doPool) {
      #pragma unroll
      for (int r = 0; r < 4; ++r) {
        float m = pm4[r], s = ps4[r];
        m = fmaxf(m, __shfl_xor(m, 1)); s += __shfl_xor(s, 1);
        m = fmaxf(m, __shfl_xor(m, 2)); s += __shfl_xor(s, 2);
        m = fmaxf(m, __shfl_xor(m, 4)); s += __shfl_xor(s, 4);
        m = fmaxf(m, __shfl_xor(m, 8)); s += __shfl_xor(s, 8);
        if (l15 == 0) { lpm[wave][ot * 16 + quad * 4 + r] = m; lps[wave][ot * 16 + quad * 4 + r] = s; }
      }
    }
  }
  if (doPool) {
    __syncthreads();
    if (tid < 128) {
      int wcx = tid >> 6, ol = tid & 63;
      float m = fmaxf(lpm[wcx][ol], lpm[wcx + 2][ol]);
      float s = lps[wcx][ol] + lps[wcx + 2][ol];
      int o = o0 + wcx * 64 + ol;
      pmax[((long)b * 16 + blockIdx.x) * 1024 + o] = m;
      psum[((long)b * 16 + blockIdx.x) * 1024 + o] = s;
    }
  }
}

// ---------------------------------------------------------------------------
// Channel-output MFMA GEMM (unswapped): out[o][n] fp32 or bf16; O guarded.
// ---------------------------------------------------------------------------
template <int TM>
__global__ __launch_bounds__(256, 4)
void gemm_chan(const unsigned short* __restrict__ Wb, int ldW,
               const unsigned short* __restrict__ A, long sA, int ldA,
               const float* __restrict__ biasF,
               float* __restrict__ outF, long sOutF, int ldOutF,
               unsigned short* __restrict__ outH, long sOutH, int ldOutH,
               int K, int O, int act) {
  constexpr int MT = TM / 32;
  __shared__ unsigned short lA[TM * 64];
  __shared__ unsigned short lB[128 * 64];
  int tid = threadIdx.x;
  int n0 = blockIdx.x * TM, o0 = blockIdx.y * 128, b = blockIdx.z;
  int wave = tid >> 6, lane = tid & 63;
  int wr = wave >> 1, wc = wave & 1;
  int quad = lane >> 4, l15 = lane & 15;
  int rowL = lane >> 3;
  int kseg = (lane & 7) ^ rowL;
  const unsigned short* Ab = A + (long)b * sA + (long)n0 * ldA;
  const unsigned short* Wp = Wb + (long)o0 * ldW;

  f32x4 acc[MT][4];
  #pragma unroll
  for (int i = 0; i < MT; ++i)
    #pragma unroll
    for (int j = 0; j < 4; ++j) acc[i][j] = (f32x4){0.f, 0.f, 0.f, 0.f};

  for (int kc = 0; kc < K; kc += 64) {
    #pragma unroll
    for (int t = 0; t < 4; ++t) {
      int chunk = t * 4 + wave;
      dma16(Wp + (long)(chunk * 8 + rowL) * ldW + kc + kseg * 8, &lB[chunk * 512]);
      if (chunk < TM / 8)
        dma16(Ab + (long)(chunk * 8 + rowL) * ldA + kc + kseg * 8, &lA[chunk * 512]);
    }
    __syncthreads();
    #pragma unroll
    for (int kk = 0; kk < 2; ++kk) {
      short8 af[MT], bf[4];
      #pragma unroll
      for (int mt = 0; mt < MT; ++mt) {
        int r = wr * (TM / 2) + mt * 16 + l15;
        af[mt] = *(const short8*)&lA[r * 64 + (((kk * 4 + quad) ^ (l15 & 7)) * 8)];
      }
      #pragma unroll
      for (int ot = 0; ot < 4; ++ot) {
        int r = wc * 64 + ot * 16 + l15;
        bf[ot] = *(const short8*)&lB[r * 64 + (((kk * 4 + quad) ^ (l15 & 7)) * 8)];
      }
      #pragma unroll
      for (int mt = 0; mt < MT; ++mt)
        #pragma unroll
        for (int ot = 0; ot < 4; ++ot)
          acc[mt][ot] = __builtin_amdgcn_mfma_f32_16x16x32_bf16(af[mt], bf[ot], acc[mt][ot], 0, 0, 0);
    }
    __syncthreads();
  }

  #pragma unroll
  for (int ot = 0; ot < 4; ++ot) {
    int o = o0 + wc * 64 + ot * 16 + l15;
    if (o >= O) continue;
    float bi = biasF ? biasF[o] : 0.f;
    #pragma unroll
    for (int mt = 0; mt < MT; ++mt) {
      int nb = n0 + wr * (TM / 2) + mt * 16 + quad * 4;
      float vals[4];
      #pragma unroll
      for (int r = 0; r < 4; ++r) {
        float val = acc[mt][ot][r] + bi;
        if (act == 1)      val = fmaxf(val, 0.f);
        else if (act == 2) val = (val >= 0.f) ? val : 0.2f * val;
        vals[r] = val;
      }
      if (outF)
        *(float4*)&outF[(long)b * sOutF + (long)o * ldOutF + nb] = *(float4*)vals;
      if (outH) {
        unsigned short t[4];
        #pragma unroll
        for (int r = 0; r < 4; ++r) t[r] = f2bf(vals[r]);
        *(uint2*)&outH[(long)b * sOutH + (long)o * ldOutH + nb] = *(uint2*)&t[0];
      }
    }
  }
}

// ---------------------------------------------------------------------------
// Gram row-stats -> lw[n] = mx[n] + log(rs[n]).  E = xk xk^T, K=128.
// ---------------------------------------------------------------------------
__global__ __launch_bounds__(256)
void gram_lw(const unsigned short* __restrict__ xk, long sXk,
             float* __restrict__ lw) {
  __shared__ unsigned short lK[64 * 128];
  int tid = threadIdx.x, wave = tid >> 6, lane = tid & 63;
  int quad = lane >> 4, l15 = lane & 15;
  int rowL4 = lane >> 4, s16 = lane & 15;
  int n0 = blockIdx.x * 64, b = blockIdx.y;
  const unsigned short* Kp = xk + (long)b * sXk;
  short8 afr[4];
  {
    const unsigned short* arow = Kp + (long)(n0 + wave * 16 + l15) * 128;
    #pragma unroll
    for (int kf = 0; kf < 4; ++kf) afr[kf] = *(const short8*)(arow + kf * 32 + quad * 8);
  }
  float runm[4], runs[4];
  #pragma unroll
  for (int r = 0; r < 4; ++r) { runm[r] = -1e30f; runs[r] = 0.f; }

  for (int m0 = 0; m0 < 2048; m0 += 64) {
    __syncthreads();
    #pragma unroll
    for (int t = 0; t < 4; ++t) {
      int c = t * 4 + wave;
      int row = c * 4 + rowL4;
      int gseg = (s16 & 8) | ((s16 ^ (row & 7)) & 7);
      dma16(Kp + (long)(m0 + row) * 128 + gseg * 8, &lK[c * 512]);
    }
    __syncthreads();
    #pragma unroll
    for (int mf = 0; mf < 4; ++mf) {
      f32x4 s = (f32x4){0.f, 0.f, 0.f, 0.f};
      #pragma unroll
      for (int kf = 0; kf < 4; ++kf) {
        int r = mf * 16 + l15, q = kf * 4 + quad;
        int sp = (q & 8) | ((q ^ (r & 7)) & 7);
        short8 bfr = *(const short8*)&lK[r * 128 + sp * 8];
        s = __builtin_amdgcn_mfma_f32_16x16x32_bf16(afr[kf], bfr, s, 0, 0, 0);
      }
      #pragma unroll
      for (int r = 0; r < 4; ++r) {
        float e = s[r];
        float mn = fmaxf(runm[r], e);
        runs[r] = runs[r] * __expf(runm[r] - mn) + __expf(e - mn);
        runm[r] = mn;
      }
    }
  }
  #pragma unroll
  for (int r = 0; r < 4; ++r) {
    float m = runm[r], s = runs[r];
    #pragma unroll
    for (int off = 1; off < 16; off <<= 1) {
      float mo = __shfl_xor(m, off), so = __shfl_xor(s, off);
      float mn = fmaxf(m, mo);
      s = s * __expf(m - mn) + so * __expf(mo - mn);
      m = mn;
    }
    if (l15 == 0) {
      int n = n0 + wave * 16 + quad * 4 + r;
      lw[(long)b * 2048 + n] = m + __logf(s);
    }
  }
}

// ---------------------------------------------------------------------------
// Fused PV: p[m][n] = exp(E[m][n] - lw[n]);  cs[m] = sum_n p;
// xrb[m][d] = bf16( li[m][d] - (sum_n p[m][n]*xv[d][n]) / (1e-9+cs[m]) )
// ---------------------------------------------------------------------------
__global__ __launch_bounds__(256)
void pv_k(const unsigned short* __restrict__ xk, long sXk,
          const unsigned short* __restrict__ xv, long sXv,
          const float* __restrict__ lw,
          const float* __restrict__ li, long sLi, int ldLi,
          unsigned short* __restrict__ xrb, long sXr) {
  __shared__ unsigned short lK[64 * 128];
  __shared__ unsigned short lV[128 * 64];
  __shared__ unsigned short lP[4][16 * 72];
  __shared__ float lwt[64];
  int tid = threadIdx.x, wave = tid >> 6, lane = tid & 63;
  int quad = lane >> 4, l15 = lane & 15;
  int rowL4 = lane >> 4, s16 = lane & 15;
  int rowL8 = lane >> 3, s8 = lane & 7;
  int m0 = blockIdx.x * 64, b = blockIdx.y;
  const unsigned short* Kp = xk + (long)b * sXk;
  const unsigned short* Vp = xv + (long)b * sXv;
  short8 akr[4];
  {
    const unsigned short* arow = Kp + (long)(m0 + wave * 16 + l15) * 128;
    #pragma unroll
    for (int kf = 0; kf < 4; ++kf) akr[kf] = *(const short8*)(arow + kf * 32 + quad * 8);
  }
  f32x4 acc[8];
  #pragma unroll
  for (int dt = 0; dt < 8; ++dt) acc[dt] = (f32x4){0.f, 0.f, 0.f, 0.f};
  float runc[4] = {0.f, 0.f, 0.f, 0.f};

  for (int n0c = 0; n0c < 2048; n0c += 64) {
    __syncthreads();
    #pragma unroll
    for (int t = 0; t < 4; ++t) {
      int cK = t * 4 + wave;
      int rowK = cK * 4 + rowL4;
      int gsegK = (s16 & 8) | ((s16 ^ (rowK & 7)) & 7);
      dma16(Kp + (long)(n0c + rowK) * 128 + gsegK * 8, &lK[cK * 512]);
      int cV = t * 4 + wave;
      int rowV = cV * 8 + rowL8;
      int gsegV = s8 ^ (rowV & 7);
      dma16(Vp + (long)rowV * 2048 + n0c + gsegV * 8, &lV[cV * 512]);
    }
    if (tid < 64) lwt[tid] = lw[(long)b * 2048 + n0c + tid];
    __syncthreads();
    #pragma unroll
    for (int nf = 0; nf < 4; ++nf) {
      f32x4 s = (f32x4){0.f, 0.f, 0.f, 0.f};
      #pragma unroll
      for (int kf = 0; kf < 4; ++kf) {
        int r = nf * 16 + l15, q = kf * 4 + quad;
        int sp = (q & 8) | ((q ^ (r & 7)) & 7);
        short8 bfr = *(const short8*)&lK[r * 128 + sp * 8];
        s = __builtin_amdgcn_mfma_f32_16x16x32_bf16(akr[kf], bfr, s, 0, 0, 0);
      }
      float lwc = lwt[nf * 16 + l15];
      #pragma unroll
      for (int r = 0; r < 4; ++r) {
        float p = __expf(s[r] - lwc);
        runc[r] += p;
        lP[wave][(quad * 4 + r) * 72 + nf * 16 + l15] = f2bf(p);
      }
    }
    __syncthreads();
    #pragma unroll
    for (int kc = 0; kc < 2; ++kc) {
      short8 pa = *(const short8*)&lP[wave][l15 * 72 + kc * 32 + quad * 8];
      #pragma unroll
      for (int dt = 0; dt < 8; ++dt) {
        int r = dt * 16 + l15, q = kc * 4 + quad;
        int sp = q ^ (r & 7);
        short8 vb = *(const short8*)&lV[r * 64 + sp * 8];
        acc[dt] = __builtin_amdgcn_mfma_f32_16x16x32_bf16(pa, vb, acc[dt], 0, 0, 0);
      }
    }
  }
  float inv[4];
  #pragma unroll
  for (int r = 0; r < 4; ++r) {
    float s = runc[r];
    #pragma unroll
    for (int off = 1; off < 16; off <<= 1) s += __shfl_xor(s, off);
    inv[r] = 1.f / (1e-9f + s);
  }
  #pragma unroll
  for (int dt = 0; dt < 8; ++dt) {
    int d = dt * 16 + l15;
    #pragma unroll
    for (int r = 0; r < 4; ++r) {
      int m = m0 + wave * 16 + quad * 4 + r;
      float lv = li[(long)b * sLi + (long)m * ldLi + d];
      xrb[(long)b * sXr + (long)m * 128 + d] = f2bf(lv - acc[dt][r] * inv[r]);
    }
  }
}

// ---------------------------------------------------------------------------
__global__ void poolred_k(const float* __restrict__ pmax, const float* __restrict__ psum,
                          float* __restrict__ xmax, float* __restrict__ xavg) {
  int f = blockIdx.x * 256 + threadIdx.x, b = blockIdx.y;
  float mx = -1e30f, s = 0.f;
  #pragma unroll
  for (int t = 0; t < 16; ++t) {
    mx = fmaxf(mx, pmax[((long)b * 16 + t) * 1024 + f]);
    s += psum[((long)b * 16 + t) * 1024 + f];
  }
  xmax[(long)b * 1024 + f] = mx;
  xavg[(long)b * 1024 + f] = s * (1.f / 2048.f);
}

// pool term, scaled by bns1 scale (pre-BN term folded through BN):
// pt[b][o] = sc1[o] * ( ws1[o][1024:2048]�xmax + ws1[o][2048:3072]�xavg )
__global__ __launch_bounds__(256)
void poolterm_k(const float* __restrict__ ws1, const float* __restrict__ xmax,
                const float* __restrict__ xavg,
                const float* __restrict__ bg, const float* __restrict__ bv,
                float* __restrict__ pt) {
  int o = blockIdx.x, b = blockIdx.y, tid = threadIdx.x;
  const float* w = ws1 + (long)o * 3072;
  float s = 0.f;
  #pragma unroll
  for (int it = 0; it < 4; ++it) {
    int c = tid + it * 256;
    s += w[1024 + c] * xmax[(long)b * 1024 + c] + w[2048 + c] * xavg[(long)b * 1024 + c];
  }
  #pragma unroll
  for (int off = 32; off; off >>= 1) s += __shfl_xor(s, off);
  __shared__ float rsm[4];
  if ((tid & 63) == 0) rsm[tid >> 6] = s;
  __syncthreads();
  if (tid == 0) {
    float sc = bg[o] * rsqrtf(bv[o] + BN_EPS);
    pt[(long)b * H1_ + o] = sc * (rsm[0] + rsm[1] + rsm[2] + rsm[3]);
  }
}

// ---------------------------------------------------------------------------
extern "C" void kernel_launch(void* const* d_in, const int* in_sizes, int n_in,
                              void* d_out, int out_size, void* d_ws, size_t ws_size,
                              hipStream_t stream) {
  const float* x      = (const float*)d_in[0];
  const float* w1     = (const float*)d_in[1];
  const float* w2     = (const float*)d_in[2];
  const float* bn1_g  = (const float*)d_in[3];
  const float* bn1_b  = (const float*)d_in[4];
  const float* bn1_m  = (const float*)d_in[5];
  const float* bn1_v  = (const float*)d_in[6];
  const float* bn2_g  = (const float*)d_in[7];
  const float* bn2_b  = (const float*)d_in[8];
  const float* bn2_m  = (const float*)d_in[9];
  const float* bn2_v  = (const float*)d_in[10];
  const float* sa_wqk = (const float*)d_in[11];
  const float* sa_wv  = (const float*)d_in[12];
  const float* sa_bv  = (const float*)d_in[13];
  const float* sa_wt  = (const float*)d_in[14];
  const float* sa_bt  = (const float*)d_in[15];
  const float* sa_g   = (const float*)d_in[16];
  const float* sa_b   = (const float*)d_in[17];
  const float* sa_m   = (const float*)d_in[18];
  const float* sa_v   = (const float*)d_in[19];
  const float* wf     = (const float*)d_in[20];
  const float* bnf_g  = (const float*)d_in[21];
  const float* bnf_b  = (const float*)d_in[22];
  const float* bnf_m  = (const float*)d_in[23];
  const float* bnf_v  = (const float*)d_in[24];
  const float* ws1    = (const float*)d_in[25];
  const float* bs1    = (const float*)d_in[26];
  const float* bns1_g = (const float*)d_in[27];
  const float* bns1_b = (const float*)d_in[28];
  const float* bns1_m = (const float*)d_in[29];
  const float* bns1_v = (const float*)d_in[30];
  const float* ws2    = (const float*)d_in[31];
  const float* bs2    = (const float*)d_in[32];
  const float* bns2_g = (const float*)d_in[33];
  const float* bns2_b = (const float*)d_in[34];
  const float* bns2_m = (const float*)d_in[35];
  const float* bns2_v = (const float*)d_in[36];
  float* out = (float*)d_out;

  float* ws = (float*)d_ws;
  size_t off = 0;
  auto alloc  = [&](size_t n) { float* p = ws + off; off += (n + 63) & ~(size_t)63; return p; };
  auto allocH = [&](size_t n) { return (unsigned short*)alloc((n + 1) / 2); };

  // ---- fixed: folded bf16 weights + fp32 biases + reductions ----
  unsigned short* w2b  = allocH(128 * 128);
  unsigned short* wqkb = allocH(4 * 128 * 128);
  unsigned short* wvb  = allocH(4 * 128 * 128);
  unsigned short* wtb  = allocH(4 * 128 * 128);
  unsigned short* wfb  = allocH((size_t)F_ * 512);
  unsigned short* ws1b = allocH((size_t)H1_ * 1024);
  unsigned short* ws2b = allocH((size_t)128 * 512);
  float* bias_w2 = alloc(128);
  float* bias_v  = alloc(512);
  float* bias_t  = alloc(512);
  float* bias_f  = alloc(1024);
  float* bias_s1 = alloc(512);
  float* bias_s2 = alloc(128);
  float* lwB  = alloc((size_t)16 * 2048);
  float* pmax = alloc((size_t)16 * 16 * 1024);
  float* psum = alloc((size_t)16 * 16 * 1024);
  float* xmaxB = alloc((size_t)16 * 1024);
  float* xavgB = alloc((size_t)16 * 1024);
  float* ptB   = alloc((size_t)16 * 512);
  size_t fixedOff = off;

  const size_t perB = 262144 /*h1*/ + 1048576 /*feats*/ +
                      131072 /*h1b*/ + 524288 /*featsb|hs1b*/ + 1048576 /*fusedb*/ +
                      131072 /*xkb*/ + 131072 /*xvb*/ + 131072 /*xrb|h0b*/;
  size_t wsFloats = ws_size / 4;
  int Gb = 1;
  for (int c : {16, 8, 4, 2, 1}) {
    if (fixedOff + (size_t)c * perB + 4096 <= wsFloats) { Gb = c; break; }
  }

  float* h1    = alloc((size_t)Gb * 262144);
  float* feats = alloc((size_t)Gb * 1048576);
  unsigned short* h1b    = allocH((size_t)Gb * 262144);
  unsigned short* featsb = allocH((size_t)Gb * 1048576);   // hs1b aliases
  unsigned short* fusedb = allocH((size_t)Gb * 2097152);
  unsigned short* xkb    = allocH((size_t)Gb * 262144);
  unsigned short* xvb    = allocH((size_t)Gb * 262144);
  unsigned short* xrb    = allocH((size_t)Gb * 262144);    // h0b aliases
  unsigned short* h0b  = xrb;
  unsigned short* hs1b = featsb;

  // ---- one-time weight folds (BN+bias -> W', b') ----
  foldw_k<<<64, 256, 0, stream>>>(w2, 128, nullptr, bn2_g, bn2_b, bn2_m, bn2_v,
                                  w2b, bias_w2, 128, 128, 128);
  for (int i = 0; i < 4; ++i) {
    foldw_k<<<64, 256, 0, stream>>>(sa_wqk + (size_t)i * 16384, 128, nullptr,
                                    nullptr, nullptr, nullptr, nullptr,
                                    wqkb + (size_t)i * 16384, nullptr, 128, 128, 128);
    foldw_k<<<64, 256, 0, stream>>>(sa_wv + (size_t)i * 16384, 128, sa_bv + i * 128,
                                    nullptr, nullptr, nullptr, nullptr,
                                    wvb + (size_t)i * 16384, bias_v + i * 128, 128, 128, 128);
    foldw_k<<<64, 256, 0, stream>>>(sa_wt + (size_t)i * 16384, 128, sa_bt + i * 128,
                                    sa_g + i * 128, sa_b + i * 128, sa_m + i * 128, sa_v + i * 128,
                                    wtb + (size_t)i * 16384, bias_t + i * 128, 128, 128, 128);
  }
  foldw_k<<<2048, 256, 0, stream>>>(wf, 512, nullptr, bnf_g, bnf_b, bnf_m, bnf_v,
                                    wfb, bias_f, 1024, 1024, 512);
  foldw_k<<<2048, 256, 0, stream>>>(ws1, 3072, bs1, bns1_g, bns1_b, bns1_m, bns1_v,
                                    ws1b, bias_s1, 512, 512, 1024);
  foldw_k<<<256, 256, 0, stream>>>(ws2, 512, bs2, bns2_g, bns2_b, bns2_m, bns2_v,
                                   ws2b, bias_s2, 50, 128, 512);

  const long sAct = 262144, sFeat = 1048576, sFus = 2097152;
  for (int b0 = 0; b0 < B_; b0 += Gb) {
    int g = Gb;
    conv1_k<<<dim3(N_, g), 128, 0, stream>>>(x + (long)b0 * 3 * N_, w1,
                                             bn1_g, bn1_b, bn1_m, bn1_v, h0b);
    // conv2+bn2+relu -> h1 fp32 + h1b bf16
    gemm_tok<64><<<dim3(32, 1, g), 256, 0, stream>>>(
        w2b, 128, h0b, sAct, 128, bias_w2, nullptr, 0, nullptr, 0, 0,
        h1, sAct, 128, h1b, sAct, 128, nullptr, nullptr, 128, 1, 1);

    for (int i = 0; i < 4; ++i) {
      const unsigned short* lib = (i == 0) ? h1b : featsb + (size_t)(i - 1) * 128;
      const float* liF = (i == 0) ? h1 : feats + (size_t)(i - 1) * 128;
      int ldLi = (i == 0) ? 128 : 512;
      long sLi = (i == 0) ? sAct : sFeat;
      // xk (bf16 token)
      gemm_tok<64><<<dim3(32, 1, g), 256, 0, stream>>>(
          wqkb + (size_t)i * 16384, 128, lib, sLi, ldLi, nullptr, nullptr, 0,
          nullptr, 0, 0, nullptr, 0, 0, xkb, sAct, 128, nullptr, nullptr, 128, 0, 0);
      // xv (bf16 channel, +bv)
      gemm_chan<64><<<dim3(32, 1, g), 256, 0, stream>>>(
          wvb + (size_t)i * 16384, 128, lib, sLi, ldLi, bias_v + i * 128,
          nullptr, 0, 0, xvb, sAct, 2048, 128, 128, 0);
      gram_lw<<<dim3(32, g), 256, 0, stream>>>(xkb, sAct, lwB);
      pv_k<<<dim3(32, g), 256, 0, stream>>>(xkb, sAct, xvb, sAct, lwB,
                                            liF, sLi, ldLi, xrb, sAct);
      // feats_i = li + relu(wt' @ (li - xr) + bt')
      gemm_tok<64><<<dim3(32, 1, g), 256, 0, stream>>>(
          wtb + (size_t)i * 16384, 128, xrb, sAct, 128, bias_t + i * 128, nullptr, 0,
          liF, sLi, ldLi,
          feats + (size_t)i * 128, sFeat, 512,
          featsb + (size_t)i * 128, sFeat, 512, nullptr, nullptr, 128, 1, 1 | 16);
    }

    // fused = leaky(wf' @ feats + bf') -> bf16 + pool partials
    gemm_tok<128><<<dim3(16, 8, g), 256, 0, stream>>>(
        wfb, 512, featsb, sFeat, 512, bias_f, nullptr, 0, nullptr, 0, 0,
        nullptr, 0, 0, fusedb, sFus, 1024, pmax, psum, 512, 2, 32);
    poolred_k<<<dim3(4, g), 256, 0, stream>>>(pmax, psum, xmaxB, xavgB);
    poolterm_k<<<dim3(512, g), 256, 0, stream>>>(ws1, xmaxB, xavgB, bns1_g, bns1_v, ptB);
    // hs1 = relu(ws1' @ fused + bs1' + pt)
    gemm_tok<128><<<dim3(16, 4, g), 256, 0, stream>>>(
        ws1b, 1024, fusedb, sFus, 1024, bias_s1, ptB, 512, nullptr, 0, 0,
        nullptr, 0, 0, hs1b, sFeat, 512, nullptr, nullptr, 1024, 1, 0);
    // out = relu(ws2' @ hs1 + bs2') -> fp32 channel-major
    gemm_chan<64><<<dim3(32, 1, g), 256, 0, stream>>>(
        ws2b, 512, hs1b, sFeat, 512, bias_s2,
        out + (long)b0 * OUT_ * N_, (long)OUT_ * N_, 2048, nullptr, 0, 0,
        512, 50, 1);
  }
}

// Round 8
// 827.196 us; speedup vs baseline: 1.5637x; 1.0264x over previous
//
#include <hip/hip_runtime.h>
#include <cstdint>
#include <cstddef>

#define B_   16
#define N_   2048
#define D_   128
#define F_   1024
#define H1_  512
#define OUT_ 50

static constexpr float BN_EPS = 1e-5f;

typedef __attribute__((ext_vector_type(8))) short short8;
typedef __attribute__((ext_vector_type(4))) float f32x4;

__device__ inline unsigned short f2bf(float f) {
  union { float f; unsigned u; } v; v.f = f;
  unsigned r = v.u + 0x7fff + ((v.u >> 16) & 1);
  return (unsigned short)(r >> 16);
}

// async global->LDS, 16B per lane; LDS dest = wave-uniform base + lane*16
__device__ inline void dma16(const unsigned short* g, unsigned short* l) {
  __builtin_amdgcn_global_load_lds(
      (const __attribute__((address_space(1))) unsigned int*)g,
      (__attribute__((address_space(3))) unsigned int*)l, 16, 0, 0);
}

// ---------------------------------------------------------------------------
// Fold BN (+bias) into bf16 weights + fp32 bias.
// ---------------------------------------------------------------------------
__global__ void foldw_k(const float* __restrict__ W, int ldW,
                        const float* __restrict__ bias,
                        const float* __restrict__ g, const float* __restrict__ bb,
                        const float* __restrict__ m, const float* __restrict__ v,
                        unsigned short* __restrict__ Wb, float* __restrict__ biasF,
                        int O, int Opad, int K) {
  long i = (long)blockIdx.x * 256 + threadIdx.x;
  if (i >= (long)Opad * K) return;
  int o = (int)(i / K), k = (int)(i % K);
  float sc = 1.f, sh = 0.f;
  if (o < O && g) { sc = g[o] * rsqrtf(v[o] + BN_EPS); sh = bb[o] - m[o] * sc; }
  float w = (o < O) ? W[(long)o * ldW + k] * sc : 0.f;
  Wb[i] = f2bf(w);
  if (k == 0 && biasF) {
    float bf = 0.f;
    if (o < O) bf = (bias ? bias[o] : 0.f) * sc + sh;
    biasF[o] = bf;
  }
}

// ---------------------------------------------------------------------------
// conv1 (3->128) + bn + relu -> bf16 token-major. grid (N, g), block 128
// ---------------------------------------------------------------------------
__global__ void conv1_k(const float* __restrict__ x, const float* __restrict__ w1,
                        const float* __restrict__ g, const float* __restrict__ bb,
                        const float* __restrict__ m, const float* __restrict__ v,
                        unsigned short* __restrict__ h0b) {
  int o = threadIdx.x, n = blockIdx.x, b = blockIdx.y;
  const float* xb = x + (long)b * 3 * N_;
  float val = w1[o * 3 + 0] * xb[n] + w1[o * 3 + 1] * xb[N_ + n] + w1[o * 3 + 2] * xb[2 * N_ + n];
  float sc = g[o] * rsqrtf(v[o] + BN_EPS);
  val = val * sc + (bb[o] - m[o] * sc);
  h0b[((long)b * N_ + n) * D_ + o] = f2bf(fmaxf(val, 0.f));
}

// ---------------------------------------------------------------------------
// Token-output MFMA GEMM (swapped operands): out[n][o], O multiple of 128.
// Tile TM x 128, BK=64, block 256 (2x2 waves). DMA staging + XOR swizzle.
// If outF==null: bf16-only -> single-phase LDS repack, 256B-row stores.
// flags: 1 outF fp32 token | 16 add res | 32 pool partials
// ---------------------------------------------------------------------------
template <int TM>
__global__ __launch_bounds__(256, 4)
void gemm_tok(const unsigned short* __restrict__ Wb, int ldW,
              const unsigned short* __restrict__ A, long sA, int ldA,
              const float* __restrict__ biasF,
              const float* __restrict__ perBO, int ldPBO,
              const float* __restrict__ res, long sRes, int ldRes,
              float* __restrict__ outF, long sOutF, int ldOutF,
              unsigned short* __restrict__ outH, long sOutH, int ldOutH,
              float* __restrict__ pmax, float* __restrict__ psum,
              int K, int act, int flags) {
  constexpr int MT = TM / 32;
  __shared__ unsigned short lAB[TM * 64 + 128 * 64];
  __shared__ float lpm[4][64], lps[4][64];
  unsigned short* lA = lAB;
  unsigned short* lB = lAB + TM * 64;
  unsigned short* lS = lAB;                 // repack tile TM x 128 (aliases)
  int tid = threadIdx.x;
  int n0 = blockIdx.x * TM, o0 = blockIdx.y * 128, b = blockIdx.z;
  int wave = tid >> 6, lane = tid & 63;
  int wr = wave >> 1, wc = wave & 1;
  int quad = lane >> 4, l15 = lane & 15;
  int rowL = lane >> 3;
  int kseg = (lane & 7) ^ rowL;
  const unsigned short* Ab = A + (long)b * sA + (long)n0 * ldA;
  const unsigned short* Wp = Wb + (long)o0 * ldW;

  f32x4 acc[MT][4];
  #pragma unroll
  for (int i = 0; i < MT; ++i)
    #pragma unroll
    for (int j = 0; j < 4; ++j) acc[i][j] = (f32x4){0.f, 0.f, 0.f, 0.f};

  for (int kc = 0; kc < K; kc += 64) {
    #pragma unroll
    for (int t = 0; t < 4; ++t) {
      int chunk = t * 4 + wave;
      dma16(Wp + (long)(chunk * 8 + rowL) * ldW + kc + kseg * 8, &lB[chunk * 512]);
      if (chunk < TM / 8)
        dma16(Ab + (long)(chunk * 8 + rowL) * ldA + kc + kseg * 8, &lA[chunk * 512]);
    }
    __syncthreads();
    #pragma unroll
    for (int kk = 0; kk < 2; ++kk) {
      short8 af[MT], bf[4];
      #pragma unroll
      for (int mt = 0; mt < MT; ++mt) {
        int r = wr * (TM / 2) + mt * 16 + l15;
        af[mt] = *(const short8*)&lA[r * 64 + (((kk * 4 + quad) ^ (l15 & 7)) * 8)];
      }
      #pragma unroll
      for (int ot = 0; ot < 4; ++ot) {
        int r = wc * 64 + ot * 16 + l15;
        bf[ot] = *(const short8*)&lB[r * 64 + (((kk * 4 + quad) ^ (l15 & 7)) * 8)];
      }
      #pragma unroll
      for (int mt = 0; mt < MT; ++mt)
        #pragma unroll
        for (int ot = 0; ot < 4; ++ot)
          acc[mt][ot] = __builtin_amdgcn_mfma_f32_16x16x32_bf16(bf[ot], af[mt], acc[mt][ot], 0, 0, 0);
    }
    __syncthreads();
  }

  bool doPool = (flags & 32) != 0;

  if (!outF) {
    // ---- bf16-only epilogue: LDS repack -> 256B-row vector stores ----
    #pragma unroll
    for (int ot = 0; ot < 4; ++ot) {
      int obL = wc * 64 + ot * 16 + quad * 4;
      int ob = o0 + obL;
      float bi[4] = {0.f, 0.f, 0.f, 0.f};
      if (biasF) { float4 t = *(const float4*)&biasF[ob]; bi[0] = t.x; bi[1] = t.y; bi[2] = t.z; bi[3] = t.w; }
      if (perBO) {
        float4 t = *(const float4*)&perBO[(long)b * ldPBO + ob];
        bi[0] += t.x; bi[1] += t.y; bi[2] += t.z; bi[3] += t.w;
      }
      float pm4[4], ps4[4];
      #pragma unroll
      for (int r = 0; r < 4; ++r) { pm4[r] = -1e30f; ps4[r] = 0.f; }
      int g = obL >> 3, go = obL & 7;
      #pragma unroll
      for (int mt = 0; mt < MT; ++mt) {
        int nL = wr * (TM / 2) + mt * 16 + l15;
        unsigned short t4[4];
        #pragma unroll
        for (int r = 0; r < 4; ++r) {
          float val = acc[mt][ot][r] + bi[r];
          if (act == 1)      val = fmaxf(val, 0.f);
          else if (act == 2) val = (val >= 0.f) ? val : 0.2f * val;
          t4[r] = f2bf(val);
          if (doPool) { pm4[r] = fmaxf(pm4[r], val); ps4[r] += val; }
        }
        int gp = (g & 8) | ((g ^ (nL & 7)) & 7);
        *(uint2*)&lS[nL * 128 + gp * 8 + go] = *(uint2*)&t4[0];
      }
      if (doPool) {
        #pragma unroll
        for (int r = 0; r < 4; ++r) {
          float m = pm4[r], s = ps4[r];
          m = fmaxf(m, __shfl_xor(m, 1)); s += __shfl_xor(s, 1);
          m = fmaxf(m, __shfl_xor(m, 2)); s += __shfl_xor(s, 2);
          m = fmaxf(m, __shfl_xor(m, 4)); s += __shfl_xor(s, 4);
          m = fmaxf(m, __shfl_xor(m, 8)); s += __shfl_xor(s, 8);
          if (l15 == 0) { lpm[wave][ot * 16 + quad * 4 + r] = m; lps[wave][ot * 16 + quad * 4 + r] = s; }
        }
      }
    }
    __syncthreads();
    {
      int r0 = tid >> 4, s = tid & 15;
      #pragma unroll
      for (int it = 0; it < TM / 16; ++it) {
        int row = it * 16 + r0;
        int sp = (s & 8) | ((s ^ (row & 7)) & 7);
        short8 v = *(const short8*)&lS[row * 128 + sp * 8];
        *(short8*)&outH[(long)b * sOutH + (long)(n0 + row) * ldOutH + o0 + s * 8] = v;
      }
    }
    if (doPool && tid < 128) {
      int wcx = tid >> 6, ol = tid & 63;
      float m = fmaxf(lpm[wcx][ol], lpm[wcx + 2][ol]);
      float s = lps[wcx][ol] + lps[wcx + 2][ol];
      int o = o0 + wcx * 64 + ol;
      pmax[((long)b * 16 + blockIdx.x) * 1024 + o] = m;
      psum[((long)b * 16 + blockIdx.x) * 1024 + o] = s;
    }
    return;
  }

  // ---- fp32 + bf16 dual-output direct epilogue ----
  #pragma unroll
  for (int ot = 0; ot < 4; ++ot) {
    int ob = o0 + wc * 64 + ot * 16 + quad * 4;
    float bi[4] = {0.f, 0.f, 0.f, 0.f};
    if (biasF) { float4 t = *(const float4*)&biasF[ob]; bi[0] = t.x; bi[1] = t.y; bi[2] = t.z; bi[3] = t.w; }
    if (perBO) {
      float4 t = *(const float4*)&perBO[(long)b * ldPBO + ob];
      bi[0] += t.x; bi[1] += t.y; bi[2] += t.z; bi[3] += t.w;
    }
    #pragma unroll
    for (int mt = 0; mt < MT; ++mt) {
      int n = n0 + wr * (TM / 2) + mt * 16 + l15;
      float vals[4];
      #pragma unroll
      for (int r = 0; r < 4; ++r) {
        float val = acc[mt][ot][r] + bi[r];
        if (act == 1)      val = fmaxf(val, 0.f);
        else if (act == 2) val = (val >= 0.f) ? val : 0.2f * val;
        vals[r] = val;
      }
      if (flags & 16) {
        float4 t = *(const float4*)&res[(long)b * sRes + (long)n * ldRes + ob];
        vals[0] += t.x; vals[1] += t.y; vals[2] += t.z; vals[3] += t.w;
      }
      *(float4*)&outF[(long)b * sOutF + (long)n * ldOutF + ob] = *(float4*)vals;
      {
        unsigned short t[4];
        #pragma unroll
        for (int r = 0; r < 4; ++r) t[r] = f2bf(vals[r]);
        *(uint2*)&outH[(long)b * sOutH + (long)n * ldOutH + ob] = *(uint2*)&t[0];
      }
    }
  }
}

// ---------------------------------------------------------------------------
// Channel-output MFMA GEMM (unswapped): out[o][n] fp32 or bf16; O guarded.
// ---------------------------------------------------------------------------
template <int TM>
__global__ __launch_bounds__(256, 4)
void gemm_chan(const unsigned short* __restrict__ Wb, int ldW,
               const unsigned short* __restrict__ A, long sA, int ldA,
               const float* __restrict__ biasF,
               float* __restrict__ outF, long sOutF, int ldOutF,
               unsigned short* __restrict__ outH, long sOutH, int ldOutH,
               int K, int O, int act) {
  constexpr int MT = TM / 32;
  __shared__ unsigned short lA[TM * 64];
  __shared__ unsigned short lB[128 * 64];
  int tid = threadIdx.x;
  int n0 = blockIdx.x * TM, o0 = blockIdx.y * 128, b = blockIdx.z;
  int wave = tid >> 6, lane = tid & 63;
  int wr = wave >> 1, wc = wave & 1;
  int quad = lane >> 4, l15 = lane & 15;
  int rowL = lane >> 3;
  int kseg = (lane & 7) ^ rowL;
  const unsigned short* Ab = A + (long)b * sA + (long)n0 * ldA;
  const unsigned short* Wp = Wb + (long)o0 * ldW;

  f32x4 acc[MT][4];
  #pragma unroll
  for (int i = 0; i < MT; ++i)
    #pragma unroll
    for (int j = 0; j < 4; ++j) acc[i][j] = (f32x4){0.f, 0.f, 0.f, 0.f};

  for (int kc = 0; kc < K; kc += 64) {
    #pragma unroll
    for (int t = 0; t < 4; ++t) {
      int chunk = t * 4 + wave;
      dma16(Wp + (long)(chunk * 8 + rowL) * ldW + kc + kseg * 8, &lB[chunk * 512]);
      if (chunk < TM / 8)
        dma16(Ab + (long)(chunk * 8 + rowL) * ldA + kc + kseg * 8, &lA[chunk * 512]);
    }
    __syncthreads();
    #pragma unroll
    for (int kk = 0; kk < 2; ++kk) {
      short8 af[MT], bf[4];
      #pragma unroll
      for (int mt = 0; mt < MT; ++mt) {
        int r = wr * (TM / 2) + mt * 16 + l15;
        af[mt] = *(const short8*)&lA[r * 64 + (((kk * 4 + quad) ^ (l15 & 7)) * 8)];
      }
      #pragma unroll
      for (int ot = 0; ot < 4; ++ot) {
        int r = wc * 64 + ot * 16 + l15;
        bf[ot] = *(const short8*)&lB[r * 64 + (((kk * 4 + quad) ^ (l15 & 7)) * 8)];
      }
      #pragma unroll
      for (int mt = 0; mt < MT; ++mt)
        #pragma unroll
        for (int ot = 0; ot < 4; ++ot)
          acc[mt][ot] = __builtin_amdgcn_mfma_f32_16x16x32_bf16(af[mt], bf[ot], acc[mt][ot], 0, 0, 0);
    }
    __syncthreads();
  }

  #pragma unroll
  for (int ot = 0; ot < 4; ++ot) {
    int o = o0 + wc * 64 + ot * 16 + l15;
    if (o >= O) continue;
    float bi = biasF ? biasF[o] : 0.f;
    #pragma unroll
    for (int mt = 0; mt < MT; ++mt) {
      int nb = n0 + wr * (TM / 2) + mt * 16 + quad * 4;
      float vals[4];
      #pragma unroll
      for (int r = 0; r < 4; ++r) {
        float val = acc[mt][ot][r] + bi;
        if (act == 1)      val = fmaxf(val, 0.f);
        else if (act == 2) val = (val >= 0.f) ? val : 0.2f * val;
        vals[r] = val;
      }
      if (outF)
        *(float4*)&outF[(long)b * sOutF + (long)o * ldOutF + nb] = *(float4*)vals;
      if (outH) {
        unsigned short t[4];
        #pragma unroll
        for (int r = 0; r < 4; ++r) t[r] = f2bf(vals[r]);
        *(uint2*)&outH[(long)b * sOutH + (long)o * ldOutH + nb] = *(uint2*)&t[0];
      }
    }
  }
}

// ---------------------------------------------------------------------------
// Gram row-stats -> lw[n] = mx[n] + log(rs[n]).  E = xk xk^T, K=128.
// grid (g, 32): b fastest -> XCD = b%8 (L2 locality). block 256.
// ---------------------------------------------------------------------------
__global__ __launch_bounds__(256)
void gram_lw(const unsigned short* __restrict__ xk, long sXk,
             float* __restrict__ lw) {
  __shared__ unsigned short lK[64 * 128];
  int tid = threadIdx.x, wave = tid >> 6, lane = tid & 63;
  int quad = lane >> 4, l15 = lane & 15;
  int rowL4 = lane >> 4, s16 = lane & 15;
  int n0 = blockIdx.y * 64, b = blockIdx.x;
  const unsigned short* Kp = xk + (long)b * sXk;
  short8 afr[4];
  {
    const unsigned short* arow = Kp + (long)(n0 + wave * 16 + l15) * 128;
    #pragma unroll
    for (int kf = 0; kf < 4; ++kf) afr[kf] = *(const short8*)(arow + kf * 32 + quad * 8);
  }
  float runm[4], runs[4];
  #pragma unroll
  for (int r = 0; r < 4; ++r) { runm[r] = -1e30f; runs[r] = 0.f; }

  for (int m0 = 0; m0 < 2048; m0 += 64) {
    __syncthreads();
    #pragma unroll
    for (int t = 0; t < 4; ++t) {
      int c = t * 4 + wave;
      int row = c * 4 + rowL4;
      int gseg = (s16 & 8) | ((s16 ^ (row & 7)) & 7);
      dma16(Kp + (long)(m0 + row) * 128 + gseg * 8, &lK[c * 512]);
    }
    __syncthreads();
    #pragma unroll
    for (int mf = 0; mf < 4; ++mf) {
      f32x4 s = (f32x4){0.f, 0.f, 0.f, 0.f};
      #pragma unroll
      for (int kf = 0; kf < 4; ++kf) {
        int r = mf * 16 + l15, q = kf * 4 + quad;
        int sp = (q & 8) | ((q ^ (r & 7)) & 7);
        short8 bfr = *(const short8*)&lK[r * 128 + sp * 8];
        s = __builtin_amdgcn_mfma_f32_16x16x32_bf16(afr[kf], bfr, s, 0, 0, 0);
      }
      #pragma unroll
      for (int r = 0; r < 4; ++r) {
        float e = s[r];
        float mn = fmaxf(runm[r], e);
        runs[r] = runs[r] * __expf(runm[r] - mn) + __expf(e - mn);
        runm[r] = mn;
      }
    }
  }
  #pragma unroll
  for (int r = 0; r < 4; ++r) {
    float m = runm[r], s = runs[r];
    #pragma unroll
    for (int off = 1; off < 16; off <<= 1) {
      float mo = __shfl_xor(m, off), so = __shfl_xor(s, off);
      float mn = fmaxf(m, mo);
      s = s * __expf(m - mn) + so * __expf(mo - mn);
      m = mn;
    }
    if (l15 == 0) {
      int n = n0 + wave * 16 + quad * 4 + r;
      lw[(long)b * 2048 + n] = m + __logf(s);
    }
  }
}

// ---------------------------------------------------------------------------
// Fused PV: p[m][n] = exp(E[m][n] - lw[n]);  cs[m] = sum_n p;
// xrb[m][d] = bf16( li[m][d] - (sum_n p[m][n]*xv[d][n]) / (1e-9+cs[m]) )
// grid (g, 32): b fastest -> XCD = b%8.  block 256.
// ---------------------------------------------------------------------------
__global__ __launch_bounds__(256)
void pv_k(const unsigned short* __restrict__ xk, long sXk,
          const unsigned short* __restrict__ xv, long sXv,
          const float* __restrict__ lw,
          const float* __restrict__ li, long sLi, int ldLi,
          unsigned short* __restrict__ xrb, long sXr) {
  __shared__ unsigned short lK[64 * 128];
  __shared__ unsigned short lV[128 * 64];
  __shared__ unsigned short lP[4][16 * 68];   // stride 68: quads spread 8 banks
  __shared__ float lwt[64];
  int tid = threadIdx.x, wave = tid >> 6, lane = tid & 63;
  int quad = lane >> 4, l15 = lane & 15;
  int rowL4 = lane >> 4, s16 = lane & 15;
  int rowL8 = lane >> 3, s8 = lane & 7;
  int m0 = blockIdx.y * 64, b = blockIdx.x;
  const unsigned short* Kp = xk + (long)b * sXk;
  const unsigned short* Vp = xv + (long)b * sXv;
  short8 akr[4];
  {
    const unsigned short* arow = Kp + (long)(m0 + wave * 16 + l15) * 128;
    #pragma unroll
    for (int kf = 0; kf < 4; ++kf) akr[kf] = *(const short8*)(arow + kf * 32 + quad * 8);
  }
  f32x4 acc[8];
  #pragma unroll
  for (int dt = 0; dt < 8; ++dt) acc[dt] = (f32x4){0.f, 0.f, 0.f, 0.f};
  float runc[4] = {0.f, 0.f, 0.f, 0.f};

  for (int n0c = 0; n0c < 2048; n0c += 64) {
    __syncthreads();
    #pragma unroll
    for (int t = 0; t < 4; ++t) {
      int cK = t * 4 + wave;
      int rowK = cK * 4 + rowL4;
      int gsegK = (s16 & 8) | ((s16 ^ (rowK & 7)) & 7);
      dma16(Kp + (long)(n0c + rowK) * 128 + gsegK * 8, &lK[cK * 512]);
      int cV = t * 4 + wave;
      int rowV = cV * 8 + rowL8;
      int gsegV = s8 ^ (rowV & 7);
      dma16(Vp + (long)rowV * 2048 + n0c + gsegV * 8, &lV[cV * 512]);
    }
    if (tid < 64) lwt[tid] = lw[(long)b * 2048 + n0c + tid];
    __syncthreads();
    #pragma unroll
    for (int nf = 0; nf < 4; ++nf) {
      f32x4 s = (f32x4){0.f, 0.f, 0.f, 0.f};
      #pragma unroll
      for (int kf = 0; kf < 4; ++kf) {
        int r = nf * 16 + l15, q = kf * 4 + quad;
        int sp = (q & 8) | ((q ^ (r & 7)) & 7);
        short8 bfr = *(const short8*)&lK[r * 128 + sp * 8];
        s = __builtin_amdgcn_mfma_f32_16x16x32_bf16(akr[kf], bfr, s, 0, 0, 0);
      }
      float lwc = lwt[nf * 16 + l15];
      #pragma unroll
      for (int r = 0; r < 4; ++r) {
        float p = __expf(s[r] - lwc);
        runc[r] += p;
        lP[wave][(quad * 4 + r) * 68 + nf * 16 + l15] = f2bf(p);
      }
    }
    __syncthreads();
    #pragma unroll
    for (int kc = 0; kc < 2; ++kc) {
      short8 pa = *(const short8*)&lP[wave][l15 * 68 + kc * 32 + quad * 8];
      #pragma unroll
      for (int dt = 0; dt < 8; ++dt) {
        int r = dt * 16 + l15, q = kc * 4 + quad;
        int sp = q ^ (r & 7);
        short8 vb = *(const short8*)&lV[r * 64 + sp * 8];
        acc[dt] = __builtin_amdgcn_mfma_f32_16x16x32_bf16(pa, vb, acc[dt], 0, 0, 0);
      }
    }
  }
  float inv[4];
  #pragma unroll
  for (int r = 0; r < 4; ++r) {
    float s = runc[r];
    #pragma unroll
    for (int off = 1; off < 16; off <<= 1) s += __shfl_xor(s, off);
    inv[r] = 1.f / (1e-9f + s);
  }
  #pragma unroll
  for (int dt = 0; dt < 8; ++dt) {
    int d = dt * 16 + l15;
    #pragma unroll
    for (int r = 0; r < 4; ++r) {
      int m = m0 + wave * 16 + quad * 4 + r;
      float lv = li[(long)b * sLi + (long)m * ldLi + d];
      xrb[(long)b * sXr + (long)m * 128 + d] = f2bf(lv - acc[dt][r] * inv[r]);
    }
  }
}

// ---------------------------------------------------------------------------
__global__ void poolred_k(const float* __restrict__ pmax, const float* __restrict__ psum,
                          float* __restrict__ xmax, float* __restrict__ xavg) {
  int f = blockIdx.x * 256 + threadIdx.x, b = blockIdx.y;
  float mx = -1e30f, s = 0.f;
  #pragma unroll
  for (int t = 0; t < 16; ++t) {
    mx = fmaxf(mx, pmax[((long)b * 16 + t) * 1024 + f]);
    s += psum[((long)b * 16 + t) * 1024 + f];
  }
  xmax[(long)b * 1024 + f] = mx;
  xavg[(long)b * 1024 + f] = s * (1.f / 2048.f);
}

// pt[b][o] = sc1[o] * ( ws1[o][1024:2048].xmax + ws1[o][2048:3072].xavg )
__global__ __launch_bounds__(256)
void poolterm_k(const float* __restrict__ ws1, const float* __restrict__ xmax,
                const float* __restrict__ xavg,
                const float* __restrict__ bg, const float* __restrict__ bv,
                float* __restrict__ pt) {
  int o = blockIdx.x, b = blockIdx.y, tid = threadIdx.x;
  const float* w = ws1 + (long)o * 3072;
  float s = 0.f;
  #pragma unroll
  for (int it = 0; it < 4; ++it) {
    int c = tid + it * 256;
    s += w[1024 + c] * xmax[(long)b * 1024 + c] + w[2048 + c] * xavg[(long)b * 1024 + c];
  }
  #pragma unroll
  for (int off = 32; off; off >>= 1) s += __shfl_xor(s, off);
  __shared__ float rsm[4];
  if ((tid & 63) == 0) rsm[tid >> 6] = s;
  __syncthreads();
  if (tid == 0) {
    float sc = bg[o] * rsqrtf(bv[o] + BN_EPS);
    pt[(long)b * H1_ + o] = sc * (rsm[0] + rsm[1] + rsm[2] + rsm[3]);
  }
}

// ---------------------------------------------------------------------------
extern "C" void kernel_launch(void* const* d_in, const int* in_sizes, int n_in,
                              void* d_out, int out_size, void* d_ws, size_t ws_size,
                              hipStream_t stream) {
  const float* x      = (const float*)d_in[0];
  const float* w1     = (const float*)d_in[1];
  const float* w2     = (const float*)d_in[2];
  const float* bn1_g  = (const float*)d_in[3];
  const float* bn1_b  = (const float*)d_in[4];
  const float* bn1_m  = (const float*)d_in[5];
  const float* bn1_v  = (const float*)d_in[6];
  const float* bn2_g  = (const float*)d_in[7];
  const float* bn2_b  = (const float*)d_in[8];
  const float* bn2_m  = (const float*)d_in[9];
  const float* bn2_v  = (const float*)d_in[10];
  const float* sa_wqk = (const float*)d_in[11];
  const float* sa_wv  = (const float*)d_in[12];
  const float* sa_bv  = (const float*)d_in[13];
  const float* sa_wt  = (const float*)d_in[14];
  const float* sa_bt  = (const float*)d_in[15];
  const float* sa_g   = (const float*)d_in[16];
  const float* sa_b   = (const float*)d_in[17];
  const float* sa_m   = (const float*)d_in[18];
  const float* sa_v   = (const float*)d_in[19];
  const float* wf     = (const float*)d_in[20];
  const float* bnf_g  = (const float*)d_in[21];
  const float* bnf_b  = (const float*)d_in[22];
  const float* bnf_m  = (const float*)d_in[23];
  const float* bnf_v  = (const float*)d_in[24];
  const float* ws1    = (const float*)d_in[25];
  const float* bs1    = (const float*)d_in[26];
  const float* bns1_g = (const float*)d_in[27];
  const float* bns1_b = (const float*)d_in[28];
  const float* bns1_m = (const float*)d_in[29];
  const float* bns1_v = (const float*)d_in[30];
  const float* ws2    = (const float*)d_in[31];
  const float* bs2    = (const float*)d_in[32];
  const float* bns2_g = (const float*)d_in[33];
  const float* bns2_b = (const float*)d_in[34];
  const float* bns2_m = (const float*)d_in[35];
  const float* bns2_v = (const float*)d_in[36];
  float* out = (float*)d_out;

  float* ws = (float*)d_ws;
  size_t off = 0;
  auto alloc  = [&](size_t n) { float* p = ws + off; off += (n + 63) & ~(size_t)63; return p; };
  auto allocH = [&](size_t n) { return (unsigned short*)alloc((n + 1) / 2); };

  unsigned short* w2b  = allocH(128 * 128);
  unsigned short* wqkb = allocH(4 * 128 * 128);
  unsigned short* wvb  = allocH(4 * 128 * 128);
  unsigned short* wtb  = allocH(4 * 128 * 128);
  unsigned short* wfb  = allocH((size_t)F_ * 512);
  unsigned short* ws1b = allocH((size_t)H1_ * 1024);
  unsigned short* ws2b = allocH((size_t)128 * 512);
  float* bias_w2 = alloc(128);
  float* bias_v  = alloc(512);
  float* bias_t  = alloc(512);
  float* bias_f  = alloc(1024);
  float* bias_s1 = alloc(512);
  float* bias_s2 = alloc(128);
  float* lwB  = alloc((size_t)16 * 2048);
  float* pmax = alloc((size_t)16 * 16 * 1024);
  float* psum = alloc((size_t)16 * 16 * 1024);
  float* xmaxB = alloc((size_t)16 * 1024);
  float* xavgB = alloc((size_t)16 * 1024);
  float* ptB   = alloc((size_t)16 * 512);
  size_t fixedOff = off;

  const size_t perB = 262144 + 1048576 + 131072 + 524288 + 1048576 +
                      131072 + 131072 + 131072;
  size_t wsFloats = ws_size / 4;
  int Gb = 1;
  for (int c : {16, 8, 4, 2, 1}) {
    if (fixedOff + (size_t)c * perB + 4096 <= wsFloats) { Gb = c; break; }
  }

  float* h1    = alloc((size_t)Gb * 262144);
  float* feats = alloc((size_t)Gb * 1048576);
  unsigned short* h1b    = allocH((size_t)Gb * 262144);
  unsigned short* featsb = allocH((size_t)Gb * 1048576);   // hs1b aliases
  unsigned short* fusedb = allocH((size_t)Gb * 2097152);
  unsigned short* xkb    = allocH((size_t)Gb * 262144);
  unsigned short* xvb    = allocH((size_t)Gb * 262144);
  unsigned short* xrb    = allocH((size_t)Gb * 262144);    // h0b aliases
  unsigned short* h0b  = xrb;
  unsigned short* hs1b = featsb;

  foldw_k<<<64, 256, 0, stream>>>(w2, 128, nullptr, bn2_g, bn2_b, bn2_m, bn2_v,
                                  w2b, bias_w2, 128, 128, 128);
  for (int i = 0; i < 4; ++i) {
    foldw_k<<<64, 256, 0, stream>>>(sa_wqk + (size_t)i * 16384, 128, nullptr,
                                    nullptr, nullptr, nullptr, nullptr,
                                    wqkb + (size_t)i * 16384, nullptr, 128, 128, 128);
    foldw_k<<<64, 256, 0, stream>>>(sa_wv + (size_t)i * 16384, 128, sa_bv + i * 128,
                                    nullptr, nullptr, nullptr, nullptr,
                                    wvb + (size_t)i * 16384, bias_v + i * 128, 128, 128, 128);
    foldw_k<<<64, 256, 0, stream>>>(sa_wt + (size_t)i * 16384, 128, sa_bt + i * 128,
                                    sa_g + i * 128, sa_b + i * 128, sa_m + i * 128, sa_v + i * 128,
                                    wtb + (size_t)i * 16384, bias_t + i * 128, 128, 128, 128);
  }
  foldw_k<<<2048, 256, 0, stream>>>(wf, 512, nullptr, bnf_g, bnf_b, bnf_m, bnf_v,
                                    wfb, bias_f, 1024, 1024, 512);
  foldw_k<<<2048, 256, 0, stream>>>(ws1, 3072, bs1, bns1_g, bns1_b, bns1_m, bns1_v,
                                    ws1b, bias_s1, 512, 512, 1024);
  foldw_k<<<256, 256, 0, stream>>>(ws2, 512, bs2, bns2_g, bns2_b, bns2_m, bns2_v,
                                   ws2b, bias_s2, 50, 128, 512);

  const long sAct = 262144, sFeat = 1048576, sFus = 2097152;
  for (int b0 = 0; b0 < B_; b0 += Gb) {
    int g = Gb;
    conv1_k<<<dim3(N_, g), 128, 0, stream>>>(x + (long)b0 * 3 * N_, w1,
                                             bn1_g, bn1_b, bn1_m, bn1_v, h0b);
    // conv2+bn2+relu -> h1 fp32 + h1b bf16 (direct dual path)
    gemm_tok<64><<<dim3(32, 1, g), 256, 0, stream>>>(
        w2b, 128, h0b, sAct, 128, bias_w2, nullptr, 0, nullptr, 0, 0,
        h1, sAct, 128, h1b, sAct, 128, nullptr, nullptr, 128, 1, 1);

    for (int i = 0; i < 4; ++i) {
      const unsigned short* lib = (i == 0) ? h1b : featsb + (size_t)(i - 1) * 128;
      const float* liF = (i == 0) ? h1 : feats + (size_t)(i - 1) * 128;
      int ldLi = (i == 0) ? 128 : 512;
      long sLi = (i == 0) ? sAct : sFeat;
      // xk (bf16 token, repack path)
      gemm_tok<64><<<dim3(32, 1, g), 256, 0, stream>>>(
          wqkb + (size_t)i * 16384, 128, lib, sLi, ldLi, nullptr, nullptr, 0,
          nullptr, 0, 0, nullptr, 0, 0, xkb, sAct, 128, nullptr, nullptr, 128, 0, 0);
      // xv (bf16 channel, +bv)
      gemm_chan<64><<<dim3(32, 1, g), 256, 0, stream>>>(
          wvb + (size_t)i * 16384, 128, lib, sLi, ldLi, bias_v + i * 128,
          nullptr, 0, 0, xvb, sAct, 2048, 128, 128, 0);
      gram_lw<<<dim3(g, 32), 256, 0, stream>>>(xkb, sAct, lwB);
      pv_k<<<dim3(g, 32), 256, 0, stream>>>(xkb, sAct, xvb, sAct, lwB,
                                            liF, sLi, ldLi, xrb, sAct);
      // feats_i = li + relu(wt' @ (li - xr) + bt')  (dual out)
      gemm_tok<64><<<dim3(32, 1, g), 256, 0, stream>>>(
          wtb + (size_t)i * 16384, 128, xrb, sAct, 128, bias_t + i * 128, nullptr, 0,
          liF, sLi, ldLi,
          feats + (size_t)i * 128, sFeat, 512,
          featsb + (size_t)i * 128, sFeat, 512, nullptr, nullptr, 128, 1, 1 | 16);
    }

    // fused = leaky(wf' @ feats + bf') -> bf16 (repack) + pool partials
    gemm_tok<128><<<dim3(16, 8, g), 256, 0, stream>>>(
        wfb, 512, featsb, sFeat, 512, bias_f, nullptr, 0, nullptr, 0, 0,
        nullptr, 0, 0, fusedb, sFus, 1024, pmax, psum, 512, 2, 32);
    poolred_k<<<dim3(4, g), 256, 0, stream>>>(pmax, psum, xmaxB, xavgB);
    poolterm_k<<<dim3(512, g), 256, 0, stream>>>(ws1, xmaxB, xavgB, bns1_g, bns1_v, ptB);
    // hs1 = relu(ws1' @ fused + bs1' + pt) -> bf16 (repack)
    gemm_tok<128><<<dim3(16, 4, g), 256, 0, stream>>>(
        ws1b, 1024, fusedb, sFus, 1024, bias_s1, ptB, 512, nullptr, 0, 0,
        nullptr, 0, 0, hs1b, sFeat, 512, nullptr, nullptr, 1024, 1, 0);
    // out = relu(ws2' @ hs1 + bs2') -> fp32 channel-major
    gemm_chan<64><<<dim3(32, 1, g), 256, 0, stream>>>(
        ws2b, 512, hs1b, sFeat, 512, bias_s2,
        out + (long)b0 * OUT_ * N_, (long)OUT_ * N_, 2048, nullptr, 0, 0,
        512, 50, 1);
  }
}

// Round 9
// 782.648 us; speedup vs baseline: 1.6528x; 1.0569x over previous
//
#include <hip/hip_runtime.h>
#include <cstdint>
#include <cstddef>

#define B_   16
#define N_   2048
#define D_   128
#define F_   1024
#define H1_  512
#define OUT_ 50

static constexpr float BN_EPS = 1e-5f;

typedef __attribute__((ext_vector_type(8))) short short8;
typedef __attribute__((ext_vector_type(4))) float f32x4;

__device__ inline unsigned short f2bf(float f) {
  union { float f; unsigned u; } v; v.f = f;
  unsigned r = v.u + 0x7fff + ((v.u >> 16) & 1);
  return (unsigned short)(r >> 16);
}
__device__ inline float bf2f(unsigned short h) {
  union { unsigned u; float f; } v; v.u = ((unsigned)h) << 16; return v.f;
}

// async global->LDS, 16B per lane; LDS dest = wave-uniform base + lane*16
__device__ inline void dma16(const unsigned short* g, unsigned short* l) {
  __builtin_amdgcn_global_load_lds(
      (const __attribute__((address_space(1))) unsigned int*)g,
      (__attribute__((address_space(3))) unsigned int*)l, 16, 0, 0);
}

// ---------------------------------------------------------------------------
// Fold BN (+bias) into bf16 weights + fp32 bias.
// ---------------------------------------------------------------------------
__global__ void foldw_k(const float* __restrict__ W, int ldW,
                        const float* __restrict__ bias,
                        const float* __restrict__ g, const float* __restrict__ bb,
                        const float* __restrict__ m, const float* __restrict__ v,
                        unsigned short* __restrict__ Wb, float* __restrict__ biasF,
                        int O, int Opad, int K) {
  long i = (long)blockIdx.x * 256 + threadIdx.x;
  if (i >= (long)Opad * K) return;
  int o = (int)(i / K), k = (int)(i % K);
  float sc = 1.f, sh = 0.f;
  if (o < O && g) { sc = g[o] * rsqrtf(v[o] + BN_EPS); sh = bb[o] - m[o] * sc; }
  float w = (o < O) ? W[(long)o * ldW + k] * sc : 0.f;
  Wb[i] = f2bf(w);
  if (k == 0 && biasF) {
    float bf = 0.f;
    if (o < O) bf = (bias ? bias[o] : 0.f) * sc + sh;
    biasF[o] = bf;
  }
}

// ---------------------------------------------------------------------------
// conv1 (3->128) + bn + relu -> bf16 token-major. grid (N, g), block 128
// ---------------------------------------------------------------------------
__global__ void conv1_k(const float* __restrict__ x, const float* __restrict__ w1,
                        const float* __restrict__ g, const float* __restrict__ bb,
                        const float* __restrict__ m, const float* __restrict__ v,
                        unsigned short* __restrict__ h0b) {
  int o = threadIdx.x, n = blockIdx.x, b = blockIdx.y;
  const float* xb = x + (long)b * 3 * N_;
  float val = w1[o * 3 + 0] * xb[n] + w1[o * 3 + 1] * xb[N_ + n] + w1[o * 3 + 2] * xb[2 * N_ + n];
  float sc = g[o] * rsqrtf(v[o] + BN_EPS);
  val = val * sc + (bb[o] - m[o] * sc);
  h0b[((long)b * N_ + n) * D_ + o] = f2bf(fmaxf(val, 0.f));
}

// ---------------------------------------------------------------------------
// Token-output MFMA GEMM (swapped operands): out[n][o] bf16, O mult of 128.
// Tile TM x 128, BK=64, block 256 (2x2 waves). DMA staging + XOR swizzle.
// Epilogue: LDS repack -> 256B-row vector stores.
// flags: 16 add bf16 res after act | 32 pool partials
// ---------------------------------------------------------------------------
template <int TM>
__global__ __launch_bounds__(256, 4)
void gemm_tok(const unsigned short* __restrict__ Wb, int ldW,
              const unsigned short* __restrict__ A, long sA, int ldA,
              const float* __restrict__ biasF,
              const float* __restrict__ perBO, int ldPBO,
              const unsigned short* __restrict__ resH, long sRes, int ldRes,
              unsigned short* __restrict__ outH, long sOutH, int ldOutH,
              float* __restrict__ pmax, float* __restrict__ psum,
              int K, int act, int flags) {
  constexpr int MT = TM / 32;
  __shared__ unsigned short lAB[TM * 64 + 128 * 64];
  __shared__ float lpm[4][64], lps[4][64];
  unsigned short* lA = lAB;
  unsigned short* lB = lAB + TM * 64;
  unsigned short* lS = lAB;                 // repack tile TM x 128 (aliases)
  int tid = threadIdx.x;
  int n0 = blockIdx.x * TM, o0 = blockIdx.y * 128, b = blockIdx.z;
  int wave = tid >> 6, lane = tid & 63;
  int wr = wave >> 1, wc = wave & 1;
  int quad = lane >> 4, l15 = lane & 15;
  int rowL = lane >> 3;
  int kseg = (lane & 7) ^ rowL;
  const unsigned short* Ab = A + (long)b * sA + (long)n0 * ldA;
  const unsigned short* Wp = Wb + (long)o0 * ldW;

  f32x4 acc[MT][4];
  #pragma unroll
  for (int i = 0; i < MT; ++i)
    #pragma unroll
    for (int j = 0; j < 4; ++j) acc[i][j] = (f32x4){0.f, 0.f, 0.f, 0.f};

  for (int kc = 0; kc < K; kc += 64) {
    #pragma unroll
    for (int t = 0; t < 4; ++t) {
      int chunk = t * 4 + wave;
      dma16(Wp + (long)(chunk * 8 + rowL) * ldW + kc + kseg * 8, &lB[chunk * 512]);
      if (chunk < TM / 8)
        dma16(Ab + (long)(chunk * 8 + rowL) * ldA + kc + kseg * 8, &lA[chunk * 512]);
    }
    __syncthreads();
    #pragma unroll
    for (int kk = 0; kk < 2; ++kk) {
      short8 af[MT], bf[4];
      #pragma unroll
      for (int mt = 0; mt < MT; ++mt) {
        int r = wr * (TM / 2) + mt * 16 + l15;
        af[mt] = *(const short8*)&lA[r * 64 + (((kk * 4 + quad) ^ (l15 & 7)) * 8)];
      }
      #pragma unroll
      for (int ot = 0; ot < 4; ++ot) {
        int r = wc * 64 + ot * 16 + l15;
        bf[ot] = *(const short8*)&lB[r * 64 + (((kk * 4 + quad) ^ (l15 & 7)) * 8)];
      }
      #pragma unroll
      for (int mt = 0; mt < MT; ++mt)
        #pragma unroll
        for (int ot = 0; ot < 4; ++ot)
          acc[mt][ot] = __builtin_amdgcn_mfma_f32_16x16x32_bf16(bf[ot], af[mt], acc[mt][ot], 0, 0, 0);
    }
    __syncthreads();
  }

  bool doPool = (flags & 32) != 0;
  #pragma unroll
  for (int ot = 0; ot < 4; ++ot) {
    int obL = wc * 64 + ot * 16 + quad * 4;
    int ob = o0 + obL;
    float bi[4] = {0.f, 0.f, 0.f, 0.f};
    if (biasF) { float4 t = *(const float4*)&biasF[ob]; bi[0] = t.x; bi[1] = t.y; bi[2] = t.z; bi[3] = t.w; }
    if (perBO) {
      float4 t = *(const float4*)&perBO[(long)b * ldPBO + ob];
      bi[0] += t.x; bi[1] += t.y; bi[2] += t.z; bi[3] += t.w;
    }
    float pm4[4], ps4[4];
    #pragma unroll
    for (int r = 0; r < 4; ++r) { pm4[r] = -1e30f; ps4[r] = 0.f; }
    int g = obL >> 3, go = obL & 7;
    #pragma unroll
    for (int mt = 0; mt < MT; ++mt) {
      int nL = wr * (TM / 2) + mt * 16 + l15;
      float vals[4];
      #pragma unroll
      for (int r = 0; r < 4; ++r) {
        float val = acc[mt][ot][r] + bi[r];
        if (act == 1)      val = fmaxf(val, 0.f);
        else if (act == 2) val = (val >= 0.f) ? val : 0.2f * val;
        vals[r] = val;
      }
      if (flags & 16) {
        uint2 rv = *(const uint2*)&resH[(long)b * sRes + (long)(n0 + nL) * ldRes + ob];
        unsigned short rr[4];
        *(uint2*)rr = rv;
        #pragma unroll
        for (int r = 0; r < 4; ++r) vals[r] += bf2f(rr[r]);
      }
      unsigned short t4[4];
      #pragma unroll
      for (int r = 0; r < 4; ++r) {
        t4[r] = f2bf(vals[r]);
        if (doPool) { pm4[r] = fmaxf(pm4[r], vals[r]); ps4[r] += vals[r]; }
      }
      int gp = (g & 8) | ((g ^ (nL & 7)) & 7);
      *(uint2*)&lS[nL * 128 + gp * 8 + go] = *(uint2*)&t4[0];
    }
    if (doPool) {
      #pragma unroll
      for (int r = 0; r < 4; ++r) {
        float m = pm4[r], s = ps4[r];
        m = fmaxf(m, __shfl_xor(m, 1)); s += __shfl_xor(s, 1);
        m = fmaxf(m, __shfl_xor(m, 2)); s += __shfl_xor(s, 2);
        m = fmaxf(m, __shfl_xor(m, 4)); s += __shfl_xor(s, 4);
        m = fmaxf(m, __shfl_xor(m, 8)); s += __shfl_xor(s, 8);
        if (l15 == 0) { lpm[wave][ot * 16 + quad * 4 + r] = m; lps[wave][ot * 16 + quad * 4 + r] = s; }
      }
    }
  }
  __syncthreads();
  {
    int r0 = tid >> 4, s = tid & 15;
    #pragma unroll
    for (int it = 0; it < TM / 16; ++it) {
      int row = it * 16 + r0;
      int sp = (s & 8) | ((s ^ (row & 7)) & 7);
      short8 v = *(const short8*)&lS[row * 128 + sp * 8];
      *(short8*)&outH[(long)b * sOutH + (long)(n0 + row) * ldOutH + o0 + s * 8] = v;
    }
  }
  if (doPool && tid < 128) {
    int wcx = tid >> 6, ol = tid & 63;
    float m = fmaxf(lpm[wcx][ol], lpm[wcx + 2][ol]);
    float s = lps[wcx][ol] + lps[wcx + 2][ol];
    int o = o0 + wcx * 64 + ol;
    pmax[((long)b * 16 + blockIdx.x) * 1024 + o] = m;
    psum[((long)b * 16 + blockIdx.x) * 1024 + o] = s;
  }
}

// ---------------------------------------------------------------------------
// Channel-output MFMA GEMM (unswapped): out[o][n] fp32 or bf16; O guarded.
// ---------------------------------------------------------------------------
template <int TM>
__global__ __launch_bounds__(256, 4)
void gemm_chan(const unsigned short* __restrict__ Wb, int ldW,
               const unsigned short* __restrict__ A, long sA, int ldA,
               const float* __restrict__ biasF,
               float* __restrict__ outF, long sOutF, int ldOutF,
               unsigned short* __restrict__ outH, long sOutH, int ldOutH,
               int K, int O, int act) {
  constexpr int MT = TM / 32;
  __shared__ unsigned short lA[TM * 64];
  __shared__ unsigned short lB[128 * 64];
  int tid = threadIdx.x;
  int n0 = blockIdx.x * TM, o0 = blockIdx.y * 128, b = blockIdx.z;
  int wave = tid >> 6, lane = tid & 63;
  int wr = wave >> 1, wc = wave & 1;
  int quad = lane >> 4, l15 = lane & 15;
  int rowL = lane >> 3;
  int kseg = (lane & 7) ^ rowL;
  const unsigned short* Ab = A + (long)b * sA + (long)n0 * ldA;
  const unsigned short* Wp = Wb + (long)o0 * ldW;

  f32x4 acc[MT][4];
  #pragma unroll
  for (int i = 0; i < MT; ++i)
    #pragma unroll
    for (int j = 0; j < 4; ++j) acc[i][j] = (f32x4){0.f, 0.f, 0.f, 0.f};

  for (int kc = 0; kc < K; kc += 64) {
    #pragma unroll
    for (int t = 0; t < 4; ++t) {
      int chunk = t * 4 + wave;
      dma16(Wp + (long)(chunk * 8 + rowL) * ldW + kc + kseg * 8, &lB[chunk * 512]);
      if (chunk < TM / 8)
        dma16(Ab + (long)(chunk * 8 + rowL) * ldA + kc + kseg * 8, &lA[chunk * 512]);
    }
    __syncthreads();
    #pragma unroll
    for (int kk = 0; kk < 2; ++kk) {
      short8 af[MT], bf[4];
      #pragma unroll
      for (int mt = 0; mt < MT; ++mt) {
        int r = wr * (TM / 2) + mt * 16 + l15;
        af[mt] = *(const short8*)&lA[r * 64 + (((kk * 4 + quad) ^ (l15 & 7)) * 8)];
      }
      #pragma unroll
      for (int ot = 0; ot < 4; ++ot) {
        int r = wc * 64 + ot * 16 + l15;
        bf[ot] = *(const short8*)&lB[r * 64 + (((kk * 4 + quad) ^ (l15 & 7)) * 8)];
      }
      #pragma unroll
      for (int mt = 0; mt < MT; ++mt)
        #pragma unroll
        for (int ot = 0; ot < 4; ++ot)
          acc[mt][ot] = __builtin_amdgcn_mfma_f32_16x16x32_bf16(af[mt], bf[ot], acc[mt][ot], 0, 0, 0);
    }
    __syncthreads();
  }

  #pragma unroll
  for (int ot = 0; ot < 4; ++ot) {
    int o = o0 + wc * 64 + ot * 16 + l15;
    if (o >= O) continue;
    float bi = biasF ? biasF[o] : 0.f;
    #pragma unroll
    for (int mt = 0; mt < MT; ++mt) {
      int nb = n0 + wr * (TM / 2) + mt * 16 + quad * 4;
      float vals[4];
      #pragma unroll
      for (int r = 0; r < 4; ++r) {
        float val = acc[mt][ot][r] + bi;
        if (act == 1)      val = fmaxf(val, 0.f);
        else if (act == 2) val = (val >= 0.f) ? val : 0.2f * val;
        vals[r] = val;
      }
      if (outF)
        *(float4*)&outF[(long)b * sOutF + (long)o * ldOutF + nb] = *(float4*)vals;
      if (outH) {
        unsigned short t[4];
        #pragma unroll
        for (int r = 0; r < 4; ++r) t[r] = f2bf(vals[r]);
        *(uint2*)&outH[(long)b * sOutH + (long)o * ldOutH + nb] = *(uint2*)&t[0];
      }
    }
  }
}

// ---------------------------------------------------------------------------
// Gram row-stats -> lw[n] = mx[n] + log(rs[n]).  E = xk xk^T, K=128.
// grid (g, 32): b fastest -> XCD = b%8. block 256. Double-buffered LDS,
// one barrier per chunk; batched online-softmax update.
// ---------------------------------------------------------------------------
__global__ __launch_bounds__(256)
void gram_lw(const unsigned short* __restrict__ xk, long sXk,
             float* __restrict__ lw) {
  __shared__ unsigned short lK[2][64 * 128];
  int tid = threadIdx.x, wave = tid >> 6, lane = tid & 63;
  int quad = lane >> 4, l15 = lane & 15;
  int rowL4 = lane >> 4, s16 = lane & 15;
  int n0 = blockIdx.y * 64, b = blockIdx.x;
  const unsigned short* Kp = xk + (long)b * sXk;
  short8 afr[4];
  {
    const unsigned short* arow = Kp + (long)(n0 + wave * 16 + l15) * 128;
    #pragma unroll
    for (int kf = 0; kf < 4; ++kf) afr[kf] = *(const short8*)(arow + kf * 32 + quad * 8);
  }
  float runm[4], runs[4];
  #pragma unroll
  for (int r = 0; r < 4; ++r) { runm[r] = -1e30f; runs[r] = 0.f; }

  auto stage = [&](int ch, int bf) {
    #pragma unroll
    for (int t = 0; t < 4; ++t) {
      int c = t * 4 + wave;
      int row = c * 4 + rowL4;
      int gseg = (s16 & 8) | ((s16 ^ (row & 7)) & 7);
      dma16(Kp + (long)(ch * 64 + row) * 128 + gseg * 8, &lK[bf][c * 512]);
    }
  };
  stage(0, 0);

  for (int ch = 0; ch < 32; ++ch) {
    __syncthreads();
    int bf = ch & 1;
    if (ch + 1 < 32) stage(ch + 1, bf ^ 1);
    f32x4 sv[4];
    #pragma unroll
    for (int mf = 0; mf < 4; ++mf) {
      f32x4 s = (f32x4){0.f, 0.f, 0.f, 0.f};
      #pragma unroll
      for (int kf = 0; kf < 4; ++kf) {
        int r = mf * 16 + l15, q = kf * 4 + quad;
        int sp = (q & 8) | ((q ^ (r & 7)) & 7);
        short8 bfr = *(const short8*)&lK[bf][r * 128 + sp * 8];
        s = __builtin_amdgcn_mfma_f32_16x16x32_bf16(afr[kf], bfr, s, 0, 0, 0);
      }
      sv[mf] = s;
    }
    #pragma unroll
    for (int r = 0; r < 4; ++r) {
      float e0 = sv[0][r], e1 = sv[1][r], e2 = sv[2][r], e3 = sv[3][r];
      float cm = fmaxf(fmaxf(e0, e1), fmaxf(e2, e3));
      float mn = fmaxf(runm[r], cm);
      runs[r] = runs[r] * __expf(runm[r] - mn) +
                (__expf(e0 - mn) + __expf(e1 - mn)) + (__expf(e2 - mn) + __expf(e3 - mn));
      runm[r] = mn;
    }
  }
  #pragma unroll
  for (int r = 0; r < 4; ++r) {
    float m = runm[r], s = runs[r];
    #pragma unroll
    for (int off = 1; off < 16; off <<= 1) {
      float mo = __shfl_xor(m, off), so = __shfl_xor(s, off);
      float mn = fmaxf(m, mo);
      s = s * __expf(m - mn) + so * __expf(mo - mn);
      m = mn;
    }
    if (l15 == 0) {
      int n = n0 + wave * 16 + quad * 4 + r;
      lw[(long)b * 2048 + n] = m + __logf(s);
    }
  }
}

// ---------------------------------------------------------------------------
// Fused PV: p[m][n] = exp(E[m][n] - lw[n]);  cs[m] = sum_n p;
// xrb[m][d] = bf16( li[m][d] - (sum_n p[m][n]*xv[d][n]) / (1e-9+cs[m]) )
// grid (g, 32): b fastest. Double-buffered K/V, ONE barrier per chunk
// (lP is wave-private; DS pipe is in-order per wave). li is bf16.
// ---------------------------------------------------------------------------
__global__ __launch_bounds__(256)
void pv_k(const unsigned short* __restrict__ xk, long sXk,
          const unsigned short* __restrict__ xv, long sXv,
          const float* __restrict__ lw,
          const unsigned short* __restrict__ lib, long sLi, int ldLi,
          unsigned short* __restrict__ xrb, long sXr) {
  __shared__ unsigned short lK[2][64 * 128];
  __shared__ unsigned short lV[2][128 * 64];
  __shared__ unsigned short lP[4][16 * 64];   // 8-seg XOR layout (as lV)
  __shared__ float lwt[2][64];
  int tid = threadIdx.x, wave = tid >> 6, lane = tid & 63;
  int quad = lane >> 4, l15 = lane & 15;
  int rowL4 = lane >> 4, s16 = lane & 15;
  int rowL8 = lane >> 3, s8 = lane & 7;
  int m0 = blockIdx.y * 64, b = blockIdx.x;
  const unsigned short* Kp = xk + (long)b * sXk;
  const unsigned short* Vp = xv + (long)b * sXv;
  short8 akr[4];
  {
    const unsigned short* arow = Kp + (long)(m0 + wave * 16 + l15) * 128;
    #pragma unroll
    for (int kf = 0; kf < 4; ++kf) akr[kf] = *(const short8*)(arow + kf * 32 + quad * 8);
  }
  f32x4 acc[8];
  #pragma unroll
  for (int dt = 0; dt < 8; ++dt) acc[dt] = (f32x4){0.f, 0.f, 0.f, 0.f};
  float runc[4] = {0.f, 0.f, 0.f, 0.f};

  auto stage = [&](int ch, int bf) {
    #pragma unroll
    for (int t = 0; t < 4; ++t) {
      int c = t * 4 + wave;
      int rowK = c * 4 + rowL4;
      int gsegK = (s16 & 8) | ((s16 ^ (rowK & 7)) & 7);
      dma16(Kp + (long)(ch * 64 + rowK) * 128 + gsegK * 8, &lK[bf][c * 512]);
      int rowV = c * 8 + rowL8;
      int gsegV = s8 ^ (rowV & 7);
      dma16(Vp + (long)rowV * 2048 + ch * 64 + gsegV * 8, &lV[bf][c * 512]);
    }
    if (tid < 64) lwt[bf][tid] = lw[(long)b * 2048 + ch * 64 + tid];
  };
  stage(0, 0);

  for (int ch = 0; ch < 32; ++ch) {
    __syncthreads();
    int bf = ch & 1;
    if (ch + 1 < 32) stage(ch + 1, bf ^ 1);
    // QK -> p -> lP (wave-private, XOR layout)
    #pragma unroll
    for (int nf = 0; nf < 4; ++nf) {
      f32x4 s = (f32x4){0.f, 0.f, 0.f, 0.f};
      #pragma unroll
      for (int kf = 0; kf < 4; ++kf) {
        int r = nf * 16 + l15, q = kf * 4 + quad;
        int sp = (q & 8) | ((q ^ (r & 7)) & 7);
        short8 bfr = *(const short8*)&lK[bf][r * 128 + sp * 8];
        s = __builtin_amdgcn_mfma_f32_16x16x32_bf16(akr[kf], bfr, s, 0, 0, 0);
      }
      float lwc = lwt[bf][nf * 16 + l15];
      int segIn = nf * 2 + (l15 >> 3);
      #pragma unroll
      for (int r = 0; r < 4; ++r) {
        float p = __expf(s[r] - lwc);
        runc[r] += p;
        int row = quad * 4 + r;
        int seg = (segIn ^ (row & 7)) & 7;
        lP[wave][row * 64 + seg * 8 + (l15 & 7)] = f2bf(p);
      }
    }
    // PV (no barrier needed: lP wave-private, DS in-order)
    #pragma unroll
    for (int kc = 0; kc < 2; ++kc) {
      int qp = kc * 4 + quad;
      short8 pa = *(const short8*)&lP[wave][l15 * 64 + ((qp ^ (l15 & 7)) & 7) * 8];
      #pragma unroll
      for (int dt = 0; dt < 8; ++dt) {
        int r = dt * 16 + l15;
        int sp = qp ^ (r & 7);
        short8 vb = *(const short8*)&lV[bf][r * 64 + sp * 8];
        acc[dt] = __builtin_amdgcn_mfma_f32_16x16x32_bf16(pa, vb, acc[dt], 0, 0, 0);
      }
    }
  }
  float inv[4];
  #pragma unroll
  for (int r = 0; r < 4; ++r) {
    float s = runc[r];
    #pragma unroll
    for (int off = 1; off < 16; off <<= 1) s += __shfl_xor(s, off);
    inv[r] = 1.f / (1e-9f + s);
  }
  #pragma unroll
  for (int dt = 0; dt < 8; ++dt) {
    int d = dt * 16 + l15;
    #pragma unroll
    for (int r = 0; r < 4; ++r) {
      int m = m0 + wave * 16 + quad * 4 + r;
      float lv = bf2f(lib[(long)b * sLi + (long)m * ldLi + d]);
      xrb[(long)b * sXr + (long)m * 128 + d] = f2bf(lv - acc[dt][r] * inv[r]);
    }
  }
}

// ---------------------------------------------------------------------------
__global__ void poolred_k(const float* __restrict__ pmax, const float* __restrict__ psum,
                          float* __restrict__ xmax, float* __restrict__ xavg) {
  int f = blockIdx.x * 256 + threadIdx.x, b = blockIdx.y;
  float mx = -1e30f, s = 0.f;
  #pragma unroll
  for (int t = 0; t < 16; ++t) {
    mx = fmaxf(mx, pmax[((long)b * 16 + t) * 1024 + f]);
    s += psum[((long)b * 16 + t) * 1024 + f];
  }
  xmax[(long)b * 1024 + f] = mx;
  xavg[(long)b * 1024 + f] = s * (1.f / 2048.f);
}

// pt[b][o] = sc1[o] * ( ws1[o][1024:2048].xmax + ws1[o][2048:3072].xavg )
__global__ __launch_bounds__(256)
void poolterm_k(const float* __restrict__ ws1, const float* __restrict__ xmax,
                const float* __restrict__ xavg,
                const float* __restrict__ bg, const float* __restrict__ bv,
                float* __restrict__ pt) {
  int o = blockIdx.x, b = blockIdx.y, tid = threadIdx.x;
  const float* w = ws1 + (long)o * 3072;
  float s = 0.f;
  #pragma unroll
  for (int it = 0; it < 4; ++it) {
    int c = tid + it * 256;
    s += w[1024 + c] * xmax[(long)b * 1024 + c] + w[2048 + c] * xavg[(long)b * 1024 + c];
  }
  #pragma unroll
  for (int off = 32; off; off >>= 1) s += __shfl_xor(s, off);
  __shared__ float rsm[4];
  if ((tid & 63) == 0) rsm[tid >> 6] = s;
  __syncthreads();
  if (tid == 0) {
    float sc = bg[o] * rsqrtf(bv[o] + BN_EPS);
    pt[(long)b * H1_ + o] = sc * (rsm[0] + rsm[1] + rsm[2] + rsm[3]);
  }
}

// ---------------------------------------------------------------------------
extern "C" void kernel_launch(void* const* d_in, const int* in_sizes, int n_in,
                              void* d_out, int out_size, void* d_ws, size_t ws_size,
                              hipStream_t stream) {
  const float* x      = (const float*)d_in[0];
  const float* w1     = (const float*)d_in[1];
  const float* w2     = (const float*)d_in[2];
  const float* bn1_g  = (const float*)d_in[3];
  const float* bn1_b  = (const float*)d_in[4];
  const float* bn1_m  = (const float*)d_in[5];
  const float* bn1_v  = (const float*)d_in[6];
  const float* bn2_g  = (const float*)d_in[7];
  const float* bn2_b  = (const float*)d_in[8];
  const float* bn2_m  = (const float*)d_in[9];
  const float* bn2_v  = (const float*)d_in[10];
  const float* sa_wqk = (const float*)d_in[11];
  const float* sa_wv  = (const float*)d_in[12];
  const float* sa_bv  = (const float*)d_in[13];
  const float* sa_wt  = (const float*)d_in[14];
  const float* sa_bt  = (const float*)d_in[15];
  const float* sa_g   = (const float*)d_in[16];
  const float* sa_b   = (const float*)d_in[17];
  const float* sa_m   = (const float*)d_in[18];
  const float* sa_v   = (const float*)d_in[19];
  const float* wf     = (const float*)d_in[20];
  const float* bnf_g  = (const float*)d_in[21];
  const float* bnf_b  = (const float*)d_in[22];
  const float* bnf_m  = (const float*)d_in[23];
  const float* bnf_v  = (const float*)d_in[24];
  const float* ws1    = (const float*)d_in[25];
  const float* bs1    = (const float*)d_in[26];
  const float* bns1_g = (const float*)d_in[27];
  const float* bns1_b = (const float*)d_in[28];
  const float* bns1_m = (const float*)d_in[29];
  const float* bns1_v = (const float*)d_in[30];
  const float* ws2    = (const float*)d_in[31];
  const float* bs2    = (const float*)d_in[32];
  const float* bns2_g = (const float*)d_in[33];
  const float* bns2_b = (const float*)d_in[34];
  const float* bns2_m = (const float*)d_in[35];
  const float* bns2_v = (const float*)d_in[36];
  float* out = (float*)d_out;

  float* ws = (float*)d_ws;
  size_t off = 0;
  auto alloc  = [&](size_t n) { float* p = ws + off; off += (n + 63) & ~(size_t)63; return p; };
  auto allocH = [&](size_t n) { return (unsigned short*)alloc((n + 1) / 2); };

  unsigned short* w2b  = allocH(128 * 128);
  unsigned short* wqkb = allocH(4 * 128 * 128);
  unsigned short* wvb  = allocH(4 * 128 * 128);
  unsigned short* wtb  = allocH(4 * 128 * 128);
  unsigned short* wfb  = allocH((size_t)F_ * 512);
  unsigned short* ws1b = allocH((size_t)H1_ * 1024);
  unsigned short* ws2b = allocH((size_t)128 * 512);
  float* bias_w2 = alloc(128);
  float* bias_v  = alloc(512);
  float* bias_t  = alloc(512);
  float* bias_f  = alloc(1024);
  float* bias_s1 = alloc(512);
  float* bias_s2 = alloc(128);
  float* lwB  = alloc((size_t)16 * 2048);
  float* pmax = alloc((size_t)16 * 16 * 1024);
  float* psum = alloc((size_t)16 * 16 * 1024);
  float* xmaxB = alloc((size_t)16 * 1024);
  float* xavgB = alloc((size_t)16 * 1024);
  float* ptB   = alloc((size_t)16 * 512);
  size_t fixedOff = off;

  // per-batch (floats): h1b 131072 + featsb 524288 + fusedb 1048576 +
  //                     xkb 131072 + xvb 131072 + xrb 131072
  const size_t perB = 131072 + 524288 + 1048576 + 131072 + 131072 + 131072;
  size_t wsFloats = ws_size / 4;
  int Gb = 1;
  for (int c : {16, 8, 4, 2, 1}) {
    if (fixedOff + (size_t)c * perB + 4096 <= wsFloats) { Gb = c; break; }
  }

  unsigned short* h1b    = allocH((size_t)Gb * 262144);
  unsigned short* featsb = allocH((size_t)Gb * 1048576);   // hs1b aliases
  unsigned short* fusedb = allocH((size_t)Gb * 2097152);
  unsigned short* xkb    = allocH((size_t)Gb * 262144);
  unsigned short* xvb    = allocH((size_t)Gb * 262144);
  unsigned short* xrb    = allocH((size_t)Gb * 262144);    // h0b aliases
  unsigned short* h0b  = xrb;
  unsigned short* hs1b = featsb;

  foldw_k<<<64, 256, 0, stream>>>(w2, 128, nullptr, bn2_g, bn2_b, bn2_m, bn2_v,
                                  w2b, bias_w2, 128, 128, 128);
  for (int i = 0; i < 4; ++i) {
    foldw_k<<<64, 256, 0, stream>>>(sa_wqk + (size_t)i * 16384, 128, nullptr,
                                    nullptr, nullptr, nullptr, nullptr,
                                    wqkb + (size_t)i * 16384, nullptr, 128, 128, 128);
    foldw_k<<<64, 256, 0, stream>>>(sa_wv + (size_t)i * 16384, 128, sa_bv + i * 128,
                                    nullptr, nullptr, nullptr, nullptr,
                                    wvb + (size_t)i * 16384, bias_v + i * 128, 128, 128, 128);
    foldw_k<<<64, 256, 0, stream>>>(sa_wt + (size_t)i * 16384, 128, sa_bt + i * 128,
                                    sa_g + i * 128, sa_b + i * 128, sa_m + i * 128, sa_v + i * 128,
                                    wtb + (size_t)i * 16384, bias_t + i * 128, 128, 128, 128);
  }
  foldw_k<<<2048, 256, 0, stream>>>(wf, 512, nullptr, bnf_g, bnf_b, bnf_m, bnf_v,
                                    wfb, bias_f, 1024, 1024, 512);
  foldw_k<<<2048, 256, 0, stream>>>(ws1, 3072, bs1, bns1_g, bns1_b, bns1_m, bns1_v,
                                    ws1b, bias_s1, 512, 512, 1024);
  foldw_k<<<256, 256, 0, stream>>>(ws2, 512, bs2, bns2_g, bns2_b, bns2_m, bns2_v,
                                   ws2b, bias_s2, 50, 128, 512);

  const long sAct = 262144, sFeat = 1048576, sFus = 2097152;
  for (int b0 = 0; b0 < B_; b0 += Gb) {
    int g = Gb;
    conv1_k<<<dim3(N_, g), 128, 0, stream>>>(x + (long)b0 * 3 * N_, w1,
                                             bn1_g, bn1_b, bn1_m, bn1_v, h0b);
    // conv2+bn2+relu -> h1b bf16
    gemm_tok<64><<<dim3(32, 1, g), 256, 0, stream>>>(
        w2b, 128, h0b, sAct, 128, bias_w2, nullptr, 0, nullptr, 0, 0,
        h1b, sAct, 128, nullptr, nullptr, 128, 1, 0);

    for (int i = 0; i < 4; ++i) {
      const unsigned short* lib = (i == 0) ? h1b : featsb + (size_t)(i - 1) * 128;
      int ldLi = (i == 0) ? 128 : 512;
      long sLi = (i == 0) ? sAct : sFeat;
      // xk (bf16 token)
      gemm_tok<64><<<dim3(32, 1, g), 256, 0, stream>>>(
          wqkb + (size_t)i * 16384, 128, lib, sLi, ldLi, nullptr, nullptr, 0,
          nullptr, 0, 0, xkb, sAct, 128, nullptr, nullptr, 128, 0, 0);
      // xv (bf16 channel, +bv)
      gemm_chan<64><<<dim3(32, 1, g), 256, 0, stream>>>(
          wvb + (size_t)i * 16384, 128, lib, sLi, ldLi, bias_v + i * 128,
          nullptr, 0, 0, xvb, sAct, 2048, 128, 128, 0);
      gram_lw<<<dim3(g, 32), 256, 0, stream>>>(xkb, sAct, lwB);
      pv_k<<<dim3(g, 32), 256, 0, stream>>>(xkb, sAct, xvb, sAct, lwB,
                                            lib, sLi, ldLi, xrb, sAct);
      // feats_i = li + relu(wt' @ (li - xr) + bt')   (res = bf16 li)
      gemm_tok<64><<<dim3(32, 1, g), 256, 0, stream>>>(
          wtb + (size_t)i * 16384, 128, xrb, sAct, 128, bias_t + i * 128, nullptr, 0,
          lib, sLi, ldLi,
          featsb + (size_t)i * 128, sFeat, 512, nullptr, nullptr, 128, 1, 16);
    }

    // fused = leaky(wf' @ feats + bf') -> bf16 + pool partials
    gemm_tok<128><<<dim3(16, 8, g), 256, 0, stream>>>(
        wfb, 512, featsb, sFeat, 512, bias_f, nullptr, 0, nullptr, 0, 0,
        fusedb, sFus, 1024, pmax, psum, 512, 2, 32);
    poolred_k<<<dim3(4, g), 256, 0, stream>>>(pmax, psum, xmaxB, xavgB);
    poolterm_k<<<dim3(512, g), 256, 0, stream>>>(ws1, xmaxB, xavgB, bns1_g, bns1_v, ptB);
    // hs1 = relu(ws1' @ fused + bs1' + pt) -> bf16
    gemm_tok<128><<<dim3(16, 4, g), 256, 0, stream>>>(
        ws1b, 1024, fusedb, sFus, 1024, bias_s1, ptB, 512, nullptr, 0, 0,
        hs1b, sFeat, 512, nullptr, nullptr, 1024, 1, 0);
    // out = relu(ws2' @ hs1 + bs2') -> fp32 channel-major
    gemm_chan<64><<<dim3(32, 1, g), 256, 0, stream>>>(
        ws2b, 512, hs1b, sFeat, 512, bias_s2,
        out + (long)b0 * OUT_ * N_, (long)OUT_ * N_, 2048, nullptr, 0, 0,
        512, 50, 1);
  }
}